// Round 1
// 4163.141 us; speedup vs baseline: 4.7368x; 4.7368x over previous
//
#include <hip/hip_runtime.h>
#include <math.h>

typedef unsigned short u16;
typedef __attribute__((ext_vector_type(8))) __bf16 bf16x8;
typedef __attribute__((ext_vector_type(4))) float floatx4;

#define EPI_BIAS  1
#define EPI_RELU  2
#define EPI_EMBED 8

__device__ __forceinline__ float bf2f(u16 u) {
    union { unsigned int i; float f; } v; v.i = ((unsigned int)u) << 16; return v.f;
}
__device__ __forceinline__ u16 f2bf(float f) {
    union { float f; unsigned int i; } v; v.f = f;
    unsigned int x = v.i;
    return (u16)((x + 0x7fffu + ((x >> 16) & 1u)) >> 16);
}
// fp64 positional encoding (epilogue-only, embed GEMM; negligible cost)
__device__ __forceinline__ float posenc(int s, int c) {
    double e = exp((double)(c & 1022) * (-9.210340371976184 / 1024.0));
    double ang = (double)s * e;
    return (float)((c & 1) ? cos(ang) : sin(ang));
}

// ------- transpose+convert: in fp32 [R][C] -> out bf16 [C][R] (+lo term) -------
template<bool SPLIT>
__global__ __launch_bounds__(256) void transpose_f2b(
    const float* __restrict__ in, u16* __restrict__ oh, u16* __restrict__ ol,
    int R, int C) {
    __shared__ float tile[32][33];
    int bx = blockIdx.x * 32, by = blockIdx.y * 32;
    int tx = threadIdx.x & 31, ty = threadIdx.x >> 5; // ty 0..7
    #pragma unroll
    for (int i = ty; i < 32; i += 8) tile[i][tx] = in[(size_t)(by + i) * C + bx + tx];
    __syncthreads();
    #pragma unroll
    for (int i = ty; i < 32; i += 8) {
        float f = tile[tx][i];
        u16 hi = f2bf(f);
        oh[(size_t)(bx + i) * R + by + tx] = hi;
        if (SPLIT) ol[(size_t)(bx + i) * R + by + tx] = f2bf(f - bf2f(hi));
    }
}

// ---------------- GEMM: C[M][N] = A[M][K] * Bt[N][K]^T, MFMA bf16 ----------------
// AMODE: 0 = A bf16(u16). 1 = A fp32 -> bf16 hi. 2 = A fp32 -> bf16 lo (f - hi).
template<int AMODE, int EPI, bool ACCUM, bool WF, bool WB>
__global__ __launch_bounds__(256) void gemm_k(
    const void* __restrict__ Ap, const u16* __restrict__ Bt,
    const float* __restrict__ bias,
    float* __restrict__ outF, u16* __restrict__ outB,
    int M, int N, int K) {
    __shared__ alignas(16) u16 As[128 * 32];
    __shared__ alignas(16) u16 Bs[128 * 32];
    const int tid = threadIdx.x;
    const int wave = tid >> 6, lane = tid & 63;
    const int l16 = lane & 15, quad = lane >> 4;
    const int bm = blockIdx.x * 128, bn = blockIdx.y * 128;
    const int wm = (wave & 1) * 64, wn = (wave >> 1) * 64;
    const int sr = tid >> 2, sc = (tid & 3) * 8;

    const u16* Abf = (const u16*)Ap;
    const float* Af = (const float*)Ap;

    floatx4 acc[4][4];
    floatx4 zero = {0.0f, 0.0f, 0.0f, 0.0f};
    #pragma unroll
    for (int i = 0; i < 4; ++i)
        #pragma unroll
        for (int j = 0; j < 4; ++j) acc[i][j] = zero;

    for (int k0 = 0; k0 < K; k0 += 32) {
        // ---- stage A tile (128 x 32) ----
        if (AMODE == 0) {
            #pragma unroll
            for (int p = 0; p < 2; ++p) {
                uint4 v = *(const uint4*)(Abf + (size_t)(bm + sr + 64 * p) * K + k0 + sc);
                *(uint4*)&As[(sr + 64 * p) * 32 + sc] = v;
            }
        } else {
            #pragma unroll
            for (int p = 0; p < 2; ++p) {
                const float* g = Af + (size_t)(bm + sr + 64 * p) * K + k0 + sc;
                union { u16 u[8]; uint4 v; } tmp;
                #pragma unroll
                for (int j = 0; j < 8; ++j) {
                    float f = g[j];
                    u16 h = f2bf(f);                 // hi
                    if (AMODE == 2) h = f2bf(f - bf2f(h)); // lo (Sterbenz-exact residual)
                    tmp.u[j] = h;
                }
                *(uint4*)&As[(sr + 64 * p) * 32 + sc] = tmp.v;
            }
        }
        // ---- stage B tile (128 x 32) from Bt[N][K] (bf16) ----
        #pragma unroll
        for (int p = 0; p < 2; ++p) {
            uint4 v = *(const uint4*)(Bt + (size_t)(bn + sr + 64 * p) * K + k0 + sc);
            *(uint4*)&Bs[(sr + 64 * p) * 32 + sc] = v;
        }
        __syncthreads();
        bf16x8 af[4], bfr[4];
        #pragma unroll
        for (int i = 0; i < 4; ++i) af[i] = *(const bf16x8*)&As[(wm + i * 16 + l16) * 32 + quad * 8];
        #pragma unroll
        for (int j = 0; j < 4; ++j) bfr[j] = *(const bf16x8*)&Bs[(wn + j * 16 + l16) * 32 + quad * 8];
        #pragma unroll
        for (int i = 0; i < 4; ++i)
            #pragma unroll
            for (int j = 0; j < 4; ++j)
                acc[i][j] = __builtin_amdgcn_mfma_f32_16x16x32_bf16(af[i], bfr[j], acc[i][j], 0, 0, 0);
        __syncthreads();
    }

    // ---- epilogue (C/D map: col=lane&15, row=quad*4+reg) ----
    #pragma unroll
    for (int i = 0; i < 4; ++i) {
        #pragma unroll
        for (int r = 0; r < 4; ++r) {
            int row = bm + wm + i * 16 + quad * 4 + r;
            #pragma unroll
            for (int j = 0; j < 4; ++j) {
                int col = bn + wn + j * 16 + l16;
                float v = acc[i][j][r];
                if (EPI & EPI_BIAS) v += bias[col];
                if (ACCUM) v += outF[(size_t)row * N + col];
                if (EPI & EPI_EMBED) { v = v * 32.0f + posenc(row & 2047, col); }
                if (EPI & EPI_RELU) v = fmaxf(v, 0.0f);
                if (WF) outF[(size_t)row * N + col] = v;
                if (WB) outB[(size_t)row * N + col] = f2bf(v);
            }
        }
    }
}

// ---------------- attention v2: MFMA flash, split-bf16 QK^T ----------------
// grid = 64 bh * 16 qtiles; block = 256 (4 waves); each wave owns 32 q rows.
// Accuracy: S = qh*kh + ql*kh + qh*kl (fp32-level scores; layer-0 scores are
// sigma~1024 so plain bf16 QK^T would corrupt the near-argmax softmax).
// P and V single bf16 (error ~ same order as existing bf16 ctx rounding).
__global__ __launch_bounds__(256) void attn_k(
    const float* __restrict__ qkv, u16* __restrict__ ctx) {
    constexpr int KSTR = 72;  // 144 B rows: b128 frag reads 2-way (free)
    constexpr int VSTR = 72;
    constexpr int PSTR = 88;  // 176 B rows: 16B-aligned, ~4-way on u16 writes
    __shared__ alignas(16) u16 Kh[64 * KSTR];
    __shared__ alignas(16) u16 Kl[64 * KSTR];
    __shared__ alignas(16) u16 Vt[64 * VSTR];   // Vt[d][k]
    __shared__ alignas(16) u16 Ps[128 * PSTR];  // P[q][k]

    const int tid = threadIdx.x, wave = tid >> 6, lane = tid & 63;
    const int l16 = lane & 15, quad = lane >> 4;
    const int bh = blockIdx.x >> 4, qt = blockIdx.x & 15;
    const int b = bh >> 4, h = bh & 15;
    const size_t base = (size_t)b * 2048 * 3072;
    const int wq = wave * 32;
    const int koffK = 1024 + h * 64, koffV = 2048 + h * 64;

    // ---- Q fragments in registers, pre-scaled by 1/8 (exact), hi/lo split ----
    bf16x8 qh[2][2], ql[2][2];
    #pragma unroll
    for (int i = 0; i < 2; ++i) {
        const float* g = qkv + base + (size_t)(qt * 128 + wq + i * 16 + l16) * 3072 + h * 64 + quad * 8;
        #pragma unroll
        for (int kk = 0; kk < 2; ++kk) {
            float4 va = ((const float4*)(g + kk * 32))[0];
            float4 vb = ((const float4*)(g + kk * 32))[1];
            float f[8] = {va.x, va.y, va.z, va.w, vb.x, vb.y, vb.z, vb.w};
            union { u16 u[8]; bf16x8 v; } th, tl;
            #pragma unroll
            for (int j = 0; j < 8; ++j) {
                float s = f[j] * 0.125f;
                u16 hi = f2bf(s);
                th.u[j] = hi;
                tl.u[j] = f2bf(s - bf2f(hi));
            }
            qh[i][kk] = th.v; ql[i][kk] = tl.v;
        }
    }

    floatx4 acc_o[2][4];
    float mrun[2][4], lrun[2][4];
    floatx4 zf = {0.0f, 0.0f, 0.0f, 0.0f};
    #pragma unroll
    for (int i = 0; i < 2; ++i)
        #pragma unroll
        for (int j = 0; j < 4; ++j) acc_o[i][j] = zf;
    #pragma unroll
    for (int i = 0; i < 2; ++i)
        #pragma unroll
        for (int r = 0; r < 4; ++r) { mrun[i][r] = -1e30f; lrun[i][r] = 0.0f; }

    for (int c0 = 0; c0 < 2048; c0 += 64) {
        // ---- stage K chunk (64 x 64), hi/lo split ----
        {
            const int r = tid >> 2, cb = (tid & 3) * 16;
            const float* g = qkv + base + (size_t)(c0 + r) * 3072 + koffK + cb;
            float4 v0 = ((const float4*)g)[0], v1 = ((const float4*)g)[1];
            float4 v2 = ((const float4*)g)[2], v3 = ((const float4*)g)[3];
            float f[16] = {v0.x,v0.y,v0.z,v0.w, v1.x,v1.y,v1.z,v1.w,
                           v2.x,v2.y,v2.z,v2.w, v3.x,v3.y,v3.z,v3.w};
            union { u16 u[8]; uint4 q; } h0, h1, s0, s1;
            #pragma unroll
            for (int j = 0; j < 8; ++j) {
                u16 a = f2bf(f[j]);     h0.u[j] = a; s0.u[j] = f2bf(f[j]     - bf2f(a));
                u16 c = f2bf(f[8 + j]); h1.u[j] = c; s1.u[j] = f2bf(f[8 + j] - bf2f(c));
            }
            *(uint4*)&Kh[r * KSTR + cb]     = h0.q;
            *(uint4*)&Kh[r * KSTR + cb + 8] = h1.q;
            *(uint4*)&Kl[r * KSTR + cb]     = s0.q;
            *(uint4*)&Kl[r * KSTR + cb + 8] = s1.q;
        }
        // ---- stage V chunk transposed: Vt[d][k] (k-major -> conflict-free writes) ----
        {
            const int kk = lane, dg = wave * 16;
            const float* g = qkv + base + (size_t)(c0 + kk) * 3072 + koffV + dg;
            float4 v0 = ((const float4*)g)[0], v1 = ((const float4*)g)[1];
            float4 v2 = ((const float4*)g)[2], v3 = ((const float4*)g)[3];
            float f[16] = {v0.x,v0.y,v0.z,v0.w, v1.x,v1.y,v1.z,v1.w,
                           v2.x,v2.y,v2.z,v2.w, v3.x,v3.y,v3.z,v3.w};
            #pragma unroll
            for (int j = 0; j < 16; ++j) Vt[(dg + j) * VSTR + kk] = f2bf(f[j]);
        }
        __syncthreads();

        // ---- QK^T: S-tile 32q x 64k per wave, split 3-term ----
        floatx4 acc_s[2][4];
        #pragma unroll
        for (int i = 0; i < 2; ++i)
            #pragma unroll
            for (int j = 0; j < 4; ++j) acc_s[i][j] = zf;
        #pragma unroll
        for (int kk = 0; kk < 2; ++kk) {
            bf16x8 kbh[4], kbl[4];
            #pragma unroll
            for (int j = 0; j < 4; ++j) {
                kbh[j] = *(const bf16x8*)&Kh[(j * 16 + l16) * KSTR + kk * 32 + quad * 8];
                kbl[j] = *(const bf16x8*)&Kl[(j * 16 + l16) * KSTR + kk * 32 + quad * 8];
            }
            #pragma unroll
            for (int i = 0; i < 2; ++i)
                #pragma unroll
                for (int j = 0; j < 4; ++j) {
                    acc_s[i][j] = __builtin_amdgcn_mfma_f32_16x16x32_bf16(qh[i][kk], kbh[j], acc_s[i][j], 0, 0, 0);
                    acc_s[i][j] = __builtin_amdgcn_mfma_f32_16x16x32_bf16(ql[i][kk], kbh[j], acc_s[i][j], 0, 0, 0);
                    acc_s[i][j] = __builtin_amdgcn_mfma_f32_16x16x32_bf16(qh[i][kk], kbl[j], acc_s[i][j], 0, 0, 0);
                }
        }

        // ---- online softmax (rows live in (i,r), 16-lane butterfly over cols) ----
        #pragma unroll
        for (int i = 0; i < 2; ++i) {
            #pragma unroll
            for (int r = 0; r < 4; ++r) {
                float mx = fmaxf(fmaxf(acc_s[i][0][r], acc_s[i][1][r]),
                                 fmaxf(acc_s[i][2][r], acc_s[i][3][r]));
                #pragma unroll
                for (int off = 8; off; off >>= 1) mx = fmaxf(mx, __shfl_xor(mx, off));
                float nm = fmaxf(mrun[i][r], mx);
                float sc = __expf(mrun[i][r] - nm);
                mrun[i][r] = nm;
                float rs = 0.0f;
                #pragma unroll
                for (int j = 0; j < 4; ++j) {
                    float p = __expf(acc_s[i][j][r] - nm);
                    acc_s[i][j][r] = p;
                    rs += p;
                }
                #pragma unroll
                for (int off = 8; off; off >>= 1) rs += __shfl_xor(rs, off);
                lrun[i][r] = lrun[i][r] * sc + rs;
                #pragma unroll
                for (int jd = 0; jd < 4; ++jd) acc_o[i][jd][r] *= sc;
                #pragma unroll
                for (int j = 0; j < 4; ++j)
                    Ps[(wq + i * 16 + quad * 4 + r) * PSTR + j * 16 + l16] = f2bf(acc_s[i][j][r]);
            }
        }
        // wave reads only its OWN Ps rows; same-wave DS ops are in-order, the
        // asm fence stops the compiler from reordering the reads before writes.
        asm volatile("s_waitcnt lgkmcnt(0)" ::: "memory");

        // ---- PV: O[32q][64d] += P[32q][64k] * V[64k][64d] ----
        #pragma unroll
        for (int kk = 0; kk < 2; ++kk) {
            bf16x8 pa[2], vb[4];
            #pragma unroll
            for (int i = 0; i < 2; ++i)
                pa[i] = *(const bf16x8*)&Ps[(wq + i * 16 + l16) * PSTR + kk * 32 + quad * 8];
            #pragma unroll
            for (int jd = 0; jd < 4; ++jd)
                vb[jd] = *(const bf16x8*)&Vt[(jd * 16 + l16) * VSTR + kk * 32 + quad * 8];
            #pragma unroll
            for (int i = 0; i < 2; ++i)
                #pragma unroll
                for (int jd = 0; jd < 4; ++jd)
                    acc_o[i][jd] = __builtin_amdgcn_mfma_f32_16x16x32_bf16(pa[i], vb[jd], acc_o[i][jd], 0, 0, 0);
        }
        __syncthreads();  // before next chunk overwrites Kh/Kl/Vt (and Ps)
    }

    // ---- epilogue: normalize and store ctx bf16 ----
    #pragma unroll
    for (int i = 0; i < 2; ++i) {
        #pragma unroll
        for (int r = 0; r < 4; ++r) {
            float inv = 1.0f / lrun[i][r];
            size_t ro = (size_t)(b * 2048 + qt * 128 + wq + i * 16 + quad * 4 + r) * 1024 + h * 64;
            #pragma unroll
            for (int jd = 0; jd < 4; ++jd)
                ctx[ro + jd * 16 + l16] = f2bf(acc_o[i][jd][r] * inv);
        }
    }
}

// ---------------- layernorm, in-place on fp32 h; one block per row ----------------
__global__ __launch_bounds__(256) void ln_k(
    float* __restrict__ h, const float* __restrict__ g, const float* __restrict__ bb) {
    const int row = blockIdx.x, tid = threadIdx.x;
    const int wave = tid >> 6, lane = tid & 63;
    float4 v = *(const float4*)(h + (size_t)row * 1024 + tid * 4);
    float x[4] = {v.x, v.y, v.z, v.w};
    float s = x[0] + x[1] + x[2] + x[3];
    float s2 = x[0] * x[0] + x[1] * x[1] + x[2] * x[2] + x[3] * x[3];
    for (int off = 32; off; off >>= 1) { s += __shfl_xor(s, off); s2 += __shfl_xor(s2, off); }
    __shared__ float red[8];
    if (lane == 0) { red[wave] = s; red[4 + wave] = s2; }
    __syncthreads();
    s = red[0] + red[1] + red[2] + red[3];
    s2 = red[4] + red[5] + red[6] + red[7];
    float mu = s * (1.0f / 1024.0f);
    float var = s2 * (1.0f / 1024.0f) - mu * mu;
    float rs = rsqrtf(var + 1e-5f);
    float4 gg = *(const float4*)(g + tid * 4);
    float4 bp = *(const float4*)(bb + tid * 4);
    float4 o;
    o.x = (x[0] - mu) * rs * gg.x + bp.x;
    o.y = (x[1] - mu) * rs * gg.y + bp.y;
    o.z = (x[2] - mu) * rs * gg.z + bp.z;
    o.w = (x[3] - mu) * rs * gg.w + bp.w;
    *(float4*)(h + (size_t)row * 1024 + tid * 4) = o;
}

// ---------------- orchestration ----------------
extern "C" void kernel_launch(void* const* d_in, const int* in_sizes, int n_in,
                              void* d_out, int out_size, void* d_ws, size_t ws_size,
                              hipStream_t stream) {
    // ALL inputs are float32 (reference dtypes); round 2/3 NaN = reading fp32 as bf16.
    const float* x     = (const float*)d_in[0];
    const float* in_W  = (const float*)d_in[1];
    const float* in_b  = (const float*)d_in[2];
    const float* qkv_W = (const float*)d_in[3];
    const float* qkv_b = (const float*)d_in[4];
    const float* out_W = (const float*)d_in[5];
    const float* out_b = (const float*)d_in[6];
    const float* ln1_g = (const float*)d_in[7];
    const float* ln1_b = (const float*)d_in[8];
    const float* ln2_g = (const float*)d_in[9];
    const float* ln2_b = (const float*)d_in[10];
    const float* ff1_W = (const float*)d_in[11];
    const float* ff1_b = (const float*)d_in[12];
    const float* ff2_W = (const float*)d_in[13];
    const float* ff2_b = (const float*)d_in[14];
    const float* fin_g = (const float*)d_in[15];
    const float* fin_b = (const float*)d_in[16];
    const float* op_W  = (const float*)d_in[17];
    const float* op_b  = (const float*)d_in[18];

    // Workspace 160 MB (<=169 MB proven available in rounds 2/3)
    size_t off = 0;
    char* wsb = (char*)d_ws;
    auto alloc = [&](size_t bytes) { void* p = wsb + off; off += (bytes + 255) & ~(size_t)255; return p; };
    u16*   BtH  = (u16*)alloc((size_t)4096 * 1024 * 2);      // 8 MB  rotating B^T (hi)
    u16*   BtL  = (u16*)alloc((size_t)3072 * 1024 * 2);      // 6 MB  rotating B^T (lo, split GEMMs)
    float* hbuf = (float*)alloc((size_t)8192 * 1024 * 4);    // 32 MB fp32 hidden (in-place resid+LN)
    float* qkvb = (float*)alloc((size_t)8192 * 3072 * 4);    // 96 MB fp32 qkv / bf16 ff scratch
    u16*   ctxb = (u16*)alloc((size_t)8192 * 1024 * 2);      // 16 MB bf16 ctx
    if (off > ws_size) return;

    dim3 tb(256);

    // ---- embed: h = (x @ in_W + b)*32 + posenc, double-split (fp32-accurate h0) ----
    transpose_f2b<true><<<dim3(32, 16), tb, 0, stream>>>(in_W, BtH, BtL, 512, 1024);
    gemm_k<1, 0, false, true, false><<<dim3(64, 8), tb, 0, stream>>>(
        x, BtH, nullptr, hbuf, nullptr, 8192, 1024, 512);                       // hi*hi
    gemm_k<1, 0, true, true, false><<<dim3(64, 8), tb, 0, stream>>>(
        x, BtL, nullptr, hbuf, nullptr, 8192, 1024, 512);                       // hi*lo
    gemm_k<2, EPI_BIAS | EPI_EMBED, true, true, false><<<dim3(64, 8), tb, 0, stream>>>(
        x, BtH, in_b, hbuf, nullptr, 8192, 1024, 512);                          // lo*hi + epilogue

    for (int L = 0; L < 4; ++L) {
        // ---- qkv ----
        if (L == 0) {
            // double-split: layer-0 scores are sigma~1024 (softmax ~ argmax) -> need ~fp32 q,k
            transpose_f2b<true><<<dim3(96, 32), tb, 0, stream>>>(
                qkv_W, BtH, BtL, 1024, 3072);
            gemm_k<1, 0, false, true, false><<<dim3(64, 24), tb, 0, stream>>>(
                hbuf, BtH, nullptr, qkvb, nullptr, 8192, 3072, 1024);
            gemm_k<1, 0, true, true, false><<<dim3(64, 24), tb, 0, stream>>>(
                hbuf, BtL, nullptr, qkvb, nullptr, 8192, 3072, 1024);
            gemm_k<2, EPI_BIAS, true, true, false><<<dim3(64, 24), tb, 0, stream>>>(
                hbuf, BtH, qkv_b, qkvb, nullptr, 8192, 3072, 1024);
        } else {
            transpose_f2b<false><<<dim3(96, 32), tb, 0, stream>>>(
                qkv_W + (size_t)L * 1024 * 3072, BtH, nullptr, 1024, 3072);
            gemm_k<1, EPI_BIAS, false, true, false><<<dim3(64, 24), tb, 0, stream>>>(
                hbuf, BtH, qkv_b + (size_t)L * 3072, qkvb, nullptr, 8192, 3072, 1024);
        }
        // ---- attention (MFMA flash) ----
        attn_k<<<dim3(1024), tb, 0, stream>>>(qkvb, ctxb);
        // ---- out-proj + residual (ACCUM into h) + LN in-place ----
        transpose_f2b<false><<<dim3(32, 32), tb, 0, stream>>>(
            out_W + (size_t)L * 1024 * 1024, BtH, nullptr, 1024, 1024);
        gemm_k<0, EPI_BIAS, true, true, false><<<dim3(64, 8), tb, 0, stream>>>(
            ctxb, BtH, out_b + (size_t)L * 1024, hbuf, nullptr, 8192, 1024, 1024);
        ln_k<<<8192, tb, 0, stream>>>(hbuf, ln1_g + (size_t)L * 1024, ln1_b + (size_t)L * 1024);
        // ---- FF ----
        transpose_f2b<false><<<dim3(128, 32), tb, 0, stream>>>(
            ff1_W + (size_t)L * 1024 * 4096, BtH, nullptr, 1024, 4096);
        gemm_k<1, EPI_BIAS | EPI_RELU, false, false, true><<<dim3(64, 32), tb, 0, stream>>>(
            hbuf, BtH, ff1_b + (size_t)L * 4096, nullptr, (u16*)qkvb, 8192, 4096, 1024);
        transpose_f2b<false><<<dim3(32, 128), tb, 0, stream>>>(
            ff2_W + (size_t)L * 4096 * 1024, BtH, nullptr, 4096, 1024);
        gemm_k<0, EPI_BIAS, true, true, false><<<dim3(64, 8), tb, 0, stream>>>(
            (u16*)qkvb, BtH, ff2_b + (size_t)L * 1024, hbuf, nullptr, 8192, 1024, 4096);
        ln_k<<<8192, tb, 0, stream>>>(hbuf, ln2_g + (size_t)L * 1024, ln2_b + (size_t)L * 1024);
    }

    // ---- final LN (in-place) + output projection -> fp32 d_out ----
    ln_k<<<8192, tb, 0, stream>>>(hbuf, fin_g, fin_b);
    transpose_f2b<false><<<dim3(32, 32), tb, 0, stream>>>(op_W, BtH, nullptr, 1024, 1024);
    gemm_k<1, EPI_BIAS, false, true, false><<<dim3(64, 8), tb, 0, stream>>>(
        hbuf, BtH, op_b, (float*)d_out, nullptr, 8192, 1024, 1024);
}

// Round 2
// 3212.234 us; speedup vs baseline: 6.1390x; 1.2960x over previous
//
#include <hip/hip_runtime.h>
#include <math.h>

typedef unsigned short u16;
typedef __attribute__((ext_vector_type(8))) __bf16 bf16x8;
typedef __attribute__((ext_vector_type(4))) float floatx4;
typedef unsigned int __attribute__((address_space(1))) g_u32;
typedef unsigned int __attribute__((address_space(3))) l_u32;

#define EPI_BIAS  1
#define EPI_RELU  2
#define EPI_EMBED 8

__device__ __forceinline__ float bf2f(u16 u) {
    union { unsigned int i; float f; } v; v.i = ((unsigned int)u) << 16; return v.f;
}
// native convert: compiler emits v_cvt_pk_bf16_f32 (RNE, bit-identical to the
// old 3-op manual round for finite inputs) — 1 op per 2 values vs 3 ops/value.
__device__ __forceinline__ u16 f2bf(float f) {
    union { __bf16 b; u16 u; } v; v.b = (__bf16)f; return v.u;
}
// async 16B global->LDS DMA (lds dest = wave-uniform base + lane*16)
__device__ __forceinline__ void gl_lds16(const void* g, void* l) {
    __builtin_amdgcn_global_load_lds((const g_u32*)g, (l_u32*)l, 16, 0, 0);
}
// fp64 positional encoding (epilogue-only, embed GEMM; negligible cost)
__device__ __forceinline__ float posenc(int s, int c) {
    double e = exp((double)(c & 1022) * (-9.210340371976184 / 1024.0));
    double ang = (double)s * e;
    return (float)((c & 1) ? cos(ang) : sin(ang));
}

// ------- transpose+convert: in fp32 [R][C] -> out bf16 [C][R] (+lo term) -------
template<bool SPLIT>
__global__ __launch_bounds__(256) void transpose_f2b(
    const float* __restrict__ in, u16* __restrict__ oh, u16* __restrict__ ol,
    int R, int C) {
    __shared__ float tile[32][33];
    int bx = blockIdx.x * 32, by = blockIdx.y * 32;
    int tx = threadIdx.x & 31, ty = threadIdx.x >> 5; // ty 0..7
    #pragma unroll
    for (int i = ty; i < 32; i += 8) tile[i][tx] = in[(size_t)(by + i) * C + bx + tx];
    __syncthreads();
    #pragma unroll
    for (int i = ty; i < 32; i += 8) {
        float f = tile[tx][i];
        u16 hi = f2bf(f);
        oh[(size_t)(bx + i) * R + by + tx] = hi;
        if (SPLIT) ol[(size_t)(bx + i) * R + by + tx] = f2bf(f - bf2f(hi));
    }
}

// ---------------- GEMM: C[M][N] = A[M][K] * Bt[N][K]^T, MFMA bf16 ----------------
// AMODE: 0 = A bf16(u16). 1 = A fp32 -> bf16 hi. 2 = A fp32 -> bf16 lo (f - hi).
template<int AMODE, int EPI, bool ACCUM, bool WF, bool WB>
__global__ __launch_bounds__(256) void gemm_k(
    const void* __restrict__ Ap, const u16* __restrict__ Bt,
    const float* __restrict__ bias,
    float* __restrict__ outF, u16* __restrict__ outB,
    int M, int N, int K) {
    __shared__ alignas(16) u16 As[128 * 32];
    __shared__ alignas(16) u16 Bs[128 * 32];
    const int tid = threadIdx.x;
    const int wave = tid >> 6, lane = tid & 63;
    const int l16 = lane & 15, quad = lane >> 4;
    const int bm = blockIdx.x * 128, bn = blockIdx.y * 128;
    const int wm = (wave & 1) * 64, wn = (wave >> 1) * 64;
    const int sr = tid >> 2, sc = (tid & 3) * 8;

    const u16* Abf = (const u16*)Ap;
    const float* Af = (const float*)Ap;

    floatx4 acc[4][4];
    floatx4 zero = {0.0f, 0.0f, 0.0f, 0.0f};
    #pragma unroll
    for (int i = 0; i < 4; ++i)
        #pragma unroll
        for (int j = 0; j < 4; ++j) acc[i][j] = zero;

    for (int k0 = 0; k0 < K; k0 += 32) {
        // ---- stage A tile (128 x 32) ----
        if (AMODE == 0) {
            // bf16 A: direct DMA (layout is tid*16B-linear => wave base + lane*16)
            #pragma unroll
            for (int p = 0; p < 2; ++p) {
                const u16* g = Abf + (size_t)(bm + sr + 64 * p) * K + k0 + sc;
                gl_lds16(g, &As[(p * 64 + (wave << 4)) * 32]);
            }
        } else {
            #pragma unroll
            for (int p = 0; p < 2; ++p) {
                const float* g = Af + (size_t)(bm + sr + 64 * p) * K + k0 + sc;
                union { u16 u[8]; uint4 v; } tmp;
                #pragma unroll
                for (int j = 0; j < 8; ++j) {
                    float f = g[j];
                    u16 h = f2bf(f);                 // hi
                    if (AMODE == 2) h = f2bf(f - bf2f(h)); // lo (Sterbenz-exact residual)
                    tmp.u[j] = h;
                }
                *(uint4*)&As[(sr + 64 * p) * 32 + sc] = tmp.v;
            }
        }
        // ---- stage B tile (128 x 32) from Bt[N][K] (bf16) via DMA ----
        #pragma unroll
        for (int p = 0; p < 2; ++p) {
            const u16* g = Bt + (size_t)(bn + sr + 64 * p) * K + k0 + sc;
            gl_lds16(g, &Bs[(p * 64 + (wave << 4)) * 32]);
        }
        __syncthreads();
        bf16x8 af[4], bfr[4];
        #pragma unroll
        for (int i = 0; i < 4; ++i) af[i] = *(const bf16x8*)&As[(wm + i * 16 + l16) * 32 + quad * 8];
        #pragma unroll
        for (int j = 0; j < 4; ++j) bfr[j] = *(const bf16x8*)&Bs[(wn + j * 16 + l16) * 32 + quad * 8];
        #pragma unroll
        for (int i = 0; i < 4; ++i)
            #pragma unroll
            for (int j = 0; j < 4; ++j)
                acc[i][j] = __builtin_amdgcn_mfma_f32_16x16x32_bf16(af[i], bfr[j], acc[i][j], 0, 0, 0);
        __syncthreads();
    }

    // ---- epilogue (C/D map: col=lane&15, row=quad*4+reg) ----
    #pragma unroll
    for (int i = 0; i < 4; ++i) {
        #pragma unroll
        for (int r = 0; r < 4; ++r) {
            int row = bm + wm + i * 16 + quad * 4 + r;
            #pragma unroll
            for (int j = 0; j < 4; ++j) {
                int col = bn + wn + j * 16 + l16;
                float v = acc[i][j][r];
                if (EPI & EPI_BIAS) v += bias[col];
                if (ACCUM) v += outF[(size_t)row * N + col];
                if (EPI & EPI_EMBED) { v = v * 32.0f + posenc(row & 2047, col); }
                if (EPI & EPI_RELU) v = fmaxf(v, 0.0f);
                if (WF) outF[(size_t)row * N + col] = v;
                if (WB) outB[(size_t)row * N + col] = f2bf(v);
            }
        }
    }
}

// ---------------- attention v3: MFMA flash, split-bf16 QK^T, dbuf pipeline -------
// grid = 64 bh * 16 qtiles; block = 256 (4 waves); each wave owns 32 q rows.
// Per chunk: ONE barrier. Prefetch chunk c+2 global->regs right after barrier
// (hides under full chunk compute of c+1); convert+LDS-write at end of chunk.
__global__ __launch_bounds__(256) void attn_k(
    const float* __restrict__ qkv, u16* __restrict__ ctx) {
    constexpr int KSTR = 72;  // 144 B rows: b128 frag reads 2-way (free)
    constexpr int VSTR = 72;
    constexpr int PSTR = 88;  // 176 B rows: 16B-aligned, 2-way on b128 reads
    __shared__ alignas(16) u16 Kh[2][64 * KSTR];
    __shared__ alignas(16) u16 Kl[2][64 * KSTR];
    __shared__ alignas(16) u16 Vt[2][64 * VSTR];   // Vt[d][k]
    __shared__ alignas(16) u16 Ps[128 * PSTR];     // P[q][k]

    const int tid = threadIdx.x, wave = tid >> 6, lane = tid & 63;
    const int l16 = lane & 15, quad = lane >> 4;
    const int bh = blockIdx.x >> 4, qt = blockIdx.x & 15;
    const int b = bh >> 4, h = bh & 15;
    const size_t base = (size_t)b * 2048 * 3072;
    const int wq = wave * 32;

    // staging address bases (fixed per thread)
    const int kr = tid >> 2, kcb = (tid & 3) * 16;
    const float* gK = qkv + base + (size_t)kr * 3072 + 1024 + h * 64 + kcb;
    const int vk = lane, vdg = wave * 16;
    const float* gV = qkv + base + (size_t)vk * 3072 + 2048 + h * 64 + vdg;

    // ---- Q fragments in registers, pre-scaled by 1/8 (exact), hi/lo split ----
    bf16x8 qh[2][2], ql[2][2];
    #pragma unroll
    for (int i = 0; i < 2; ++i) {
        const float* g = qkv + base + (size_t)(qt * 128 + wq + i * 16 + l16) * 3072 + h * 64 + quad * 8;
        #pragma unroll
        for (int kk = 0; kk < 2; ++kk) {
            float4 va = ((const float4*)(g + kk * 32))[0];
            float4 vb = ((const float4*)(g + kk * 32))[1];
            float f[8] = {va.x, va.y, va.z, va.w, vb.x, vb.y, vb.z, vb.w};
            union { u16 u[8]; bf16x8 v; } th, tl;
            #pragma unroll
            for (int j = 0; j < 8; ++j) {
                float s = f[j] * 0.125f;
                u16 hi = f2bf(s);
                th.u[j] = hi;
                tl.u[j] = f2bf(s - bf2f(hi));
            }
            qh[i][kk] = th.v; ql[i][kk] = tl.v;
        }
    }

    // prefetch registers (one K-chunk + one V-chunk per thread = 32 floats)
    float4 pk4[4], pv4[4];
    auto LOAD = [&](int c) {
        const float* g = gK + (size_t)(c * 64) * 3072;
        pk4[0] = ((const float4*)g)[0]; pk4[1] = ((const float4*)g)[1];
        pk4[2] = ((const float4*)g)[2]; pk4[3] = ((const float4*)g)[3];
        const float* g2 = gV + (size_t)(c * 64) * 3072;
        pv4[0] = ((const float4*)g2)[0]; pv4[1] = ((const float4*)g2)[1];
        pv4[2] = ((const float4*)g2)[2]; pv4[3] = ((const float4*)g2)[3];
    };
    auto STORE = [&](int bu) {
        const float* pf = (const float*)pk4;
        union { u16 u[8]; uint4 q; } h0, h1, s0, s1;
        #pragma unroll
        for (int j = 0; j < 8; ++j) {
            float a = pf[j], c2 = pf[8 + j];
            u16 ah = f2bf(a); h0.u[j] = ah; s0.u[j] = f2bf(a - bf2f(ah));
            u16 ch = f2bf(c2); h1.u[j] = ch; s1.u[j] = f2bf(c2 - bf2f(ch));
        }
        *(uint4*)&Kh[bu][kr * KSTR + kcb]     = h0.q;
        *(uint4*)&Kh[bu][kr * KSTR + kcb + 8] = h1.q;
        *(uint4*)&Kl[bu][kr * KSTR + kcb]     = s0.q;
        *(uint4*)&Kl[bu][kr * KSTR + kcb + 8] = s1.q;
        const float* vf = (const float*)pv4;
        #pragma unroll
        for (int j = 0; j < 16; ++j)
            Vt[bu][(vdg + j) * VSTR + vk] = f2bf(vf[j]);
    };

    floatx4 acc_o[2][4];
    float mrun[2][4], lrun[2][4];
    floatx4 zf = {0.0f, 0.0f, 0.0f, 0.0f};
    #pragma unroll
    for (int i = 0; i < 2; ++i)
        #pragma unroll
        for (int j = 0; j < 4; ++j) acc_o[i][j] = zf;
    #pragma unroll
    for (int i = 0; i < 2; ++i)
        #pragma unroll
        for (int r = 0; r < 4; ++r) { mrun[i][r] = -1e30f; lrun[i][r] = 0.0f; }

    // prologue: chunk0 -> buf0; chunk1 -> regs
    LOAD(0); STORE(0); LOAD(1);
    __syncthreads();

    for (int c = 0; c < 32; ++c) {
        const int cur = c & 1;

        // ---- QK^T: S-tile 32q x 64k per wave, split 3-term ----
        floatx4 acc_s[2][4];
        #pragma unroll
        for (int i = 0; i < 2; ++i)
            #pragma unroll
            for (int j = 0; j < 4; ++j) acc_s[i][j] = zf;
        #pragma unroll
        for (int kk = 0; kk < 2; ++kk) {
            bf16x8 kbh[4], kbl[4];
            #pragma unroll
            for (int j = 0; j < 4; ++j) {
                kbh[j] = *(const bf16x8*)&Kh[cur][(j * 16 + l16) * KSTR + kk * 32 + quad * 8];
                kbl[j] = *(const bf16x8*)&Kl[cur][(j * 16 + l16) * KSTR + kk * 32 + quad * 8];
            }
            #pragma unroll
            for (int i = 0; i < 2; ++i)
                #pragma unroll
                for (int j = 0; j < 4; ++j) {
                    acc_s[i][j] = __builtin_amdgcn_mfma_f32_16x16x32_bf16(qh[i][kk], kbh[j], acc_s[i][j], 0, 0, 0);
                    acc_s[i][j] = __builtin_amdgcn_mfma_f32_16x16x32_bf16(ql[i][kk], kbh[j], acc_s[i][j], 0, 0, 0);
                    acc_s[i][j] = __builtin_amdgcn_mfma_f32_16x16x32_bf16(qh[i][kk], kbl[j], acc_s[i][j], 0, 0, 0);
                }
        }

        // ---- online softmax (rows in (i,r), 16-lane butterfly over cols) ----
        #pragma unroll
        for (int i = 0; i < 2; ++i) {
            #pragma unroll
            for (int r = 0; r < 4; ++r) {
                float mx = fmaxf(fmaxf(acc_s[i][0][r], acc_s[i][1][r]),
                                 fmaxf(acc_s[i][2][r], acc_s[i][3][r]));
                #pragma unroll
                for (int off = 8; off; off >>= 1) mx = fmaxf(mx, __shfl_xor(mx, off));
                float nm = fmaxf(mrun[i][r], mx);
                float sc = __expf(mrun[i][r] - nm);
                mrun[i][r] = nm;
                float rs = 0.0f;
                #pragma unroll
                for (int j = 0; j < 4; ++j) {
                    float p = __expf(acc_s[i][j][r] - nm);
                    acc_s[i][j][r] = p;
                    rs += p;
                }
                #pragma unroll
                for (int off = 8; off; off >>= 1) rs += __shfl_xor(rs, off);
                lrun[i][r] = lrun[i][r] * sc + rs;
                #pragma unroll
                for (int jd = 0; jd < 4; ++jd) acc_o[i][jd][r] *= sc;
                #pragma unroll
                for (int j = 0; j < 4; ++j)
                    Ps[(wq + i * 16 + quad * 4 + r) * PSTR + j * 16 + l16] = f2bf(acc_s[i][j][r]);
            }
        }
        // wave reads only its OWN Ps rows; same-wave DS ops are in-order, the
        // asm fence stops the compiler reordering the reads before writes.
        asm volatile("s_waitcnt lgkmcnt(0)" ::: "memory");

        // ---- PV: O[32q][64d] += P[32q][64k] * V[64k][64d] ----
        #pragma unroll
        for (int kk = 0; kk < 2; ++kk) {
            bf16x8 pa[2], vb[4];
            #pragma unroll
            for (int i = 0; i < 2; ++i)
                pa[i] = *(const bf16x8*)&Ps[(wq + i * 16 + l16) * PSTR + kk * 32 + quad * 8];
            #pragma unroll
            for (int jd = 0; jd < 4; ++jd)
                vb[jd] = *(const bf16x8*)&Vt[cur][(jd * 16 + l16) * VSTR + kk * 32 + quad * 8];
            #pragma unroll
            for (int i = 0; i < 2; ++i)
                #pragma unroll
                for (int jd = 0; jd < 4; ++jd)
                    acc_o[i][jd] = __builtin_amdgcn_mfma_f32_16x16x32_bf16(pa[i], vb[jd], acc_o[i][jd], 0, 0, 0);
        }

        // write prefetched chunk c+1 into the other buffer, then barrier
        if (c + 1 < 32) STORE(cur ^ 1);
        __syncthreads();
        if (c + 2 < 32) LOAD(c + 2);
    }

    // ---- epilogue: normalize and store ctx bf16 ----
    #pragma unroll
    for (int i = 0; i < 2; ++i) {
        #pragma unroll
        for (int r = 0; r < 4; ++r) {
            float inv = 1.0f / lrun[i][r];
            size_t ro = (size_t)(b * 2048 + qt * 128 + wq + i * 16 + quad * 4 + r) * 1024 + h * 64;
            #pragma unroll
            for (int jd = 0; jd < 4; ++jd)
                ctx[ro + jd * 16 + l16] = f2bf(acc_o[i][jd][r] * inv);
        }
    }
}

// ---------------- layernorm, in-place on fp32 h; one block per row ----------------
__global__ __launch_bounds__(256) void ln_k(
    float* __restrict__ h, const float* __restrict__ g, const float* __restrict__ bb) {
    const int row = blockIdx.x, tid = threadIdx.x;
    const int wave = tid >> 6, lane = tid & 63;
    float4 v = *(const float4*)(h + (size_t)row * 1024 + tid * 4);
    float x[4] = {v.x, v.y, v.z, v.w};
    float s = x[0] + x[1] + x[2] + x[3];
    float s2 = x[0] * x[0] + x[1] * x[1] + x[2] * x[2] + x[3] * x[3];
    for (int off = 32; off; off >>= 1) { s += __shfl_xor(s, off); s2 += __shfl_xor(s2, off); }
    __shared__ float red[8];
    if (lane == 0) { red[wave] = s; red[4 + wave] = s2; }
    __syncthreads();
    s = red[0] + red[1] + red[2] + red[3];
    s2 = red[4] + red[5] + red[6] + red[7];
    float mu = s * (1.0f / 1024.0f);
    float var = s2 * (1.0f / 1024.0f) - mu * mu;
    float rs = rsqrtf(var + 1e-5f);
    float4 gg = *(const float4*)(g + tid * 4);
    float4 bp = *(const float4*)(bb + tid * 4);
    float4 o;
    o.x = (x[0] - mu) * rs * gg.x + bp.x;
    o.y = (x[1] - mu) * rs * gg.y + bp.y;
    o.z = (x[2] - mu) * rs * gg.z + bp.z;
    o.w = (x[3] - mu) * rs * gg.w + bp.w;
    *(float4*)(h + (size_t)row * 1024 + tid * 4) = o;
}

// ---------------- orchestration ----------------
extern "C" void kernel_launch(void* const* d_in, const int* in_sizes, int n_in,
                              void* d_out, int out_size, void* d_ws, size_t ws_size,
                              hipStream_t stream) {
    // ALL inputs are float32 (reference dtypes); round 2/3 NaN = reading fp32 as bf16.
    const float* x     = (const float*)d_in[0];
    const float* in_W  = (const float*)d_in[1];
    const float* in_b  = (const float*)d_in[2];
    const float* qkv_W = (const float*)d_in[3];
    const float* qkv_b = (const float*)d_in[4];
    const float* out_W = (const float*)d_in[5];
    const float* out_b = (const float*)d_in[6];
    const float* ln1_g = (const float*)d_in[7];
    const float* ln1_b = (const float*)d_in[8];
    const float* ln2_g = (const float*)d_in[9];
    const float* ln2_b = (const float*)d_in[10];
    const float* ff1_W = (const float*)d_in[11];
    const float* ff1_b = (const float*)d_in[12];
    const float* ff2_W = (const float*)d_in[13];
    const float* ff2_b = (const float*)d_in[14];
    const float* fin_g = (const float*)d_in[15];
    const float* fin_b = (const float*)d_in[16];
    const float* op_W  = (const float*)d_in[17];
    const float* op_b  = (const float*)d_in[18];

    // Workspace 160 MB (<=169 MB proven available in rounds 2/3)
    size_t off = 0;
    char* wsb = (char*)d_ws;
    auto alloc = [&](size_t bytes) { void* p = wsb + off; off += (bytes + 255) & ~(size_t)255; return p; };
    u16*   BtH  = (u16*)alloc((size_t)4096 * 1024 * 2);      // 8 MB  rotating B^T (hi)
    u16*   BtL  = (u16*)alloc((size_t)3072 * 1024 * 2);      // 6 MB  rotating B^T (lo, split GEMMs)
    float* hbuf = (float*)alloc((size_t)8192 * 1024 * 4);    // 32 MB fp32 hidden (in-place resid+LN)
    float* qkvb = (float*)alloc((size_t)8192 * 3072 * 4);    // 96 MB fp32 qkv / bf16 ff scratch
    u16*   ctxb = (u16*)alloc((size_t)8192 * 1024 * 2);      // 16 MB bf16 ctx
    if (off > ws_size) return;

    dim3 tb(256);

    // ---- embed: h = (x @ in_W + b)*32 + posenc, double-split (fp32-accurate h0) ----
    transpose_f2b<true><<<dim3(32, 16), tb, 0, stream>>>(in_W, BtH, BtL, 512, 1024);
    gemm_k<1, 0, false, true, false><<<dim3(64, 8), tb, 0, stream>>>(
        x, BtH, nullptr, hbuf, nullptr, 8192, 1024, 512);                       // hi*hi
    gemm_k<1, 0, true, true, false><<<dim3(64, 8), tb, 0, stream>>>(
        x, BtL, nullptr, hbuf, nullptr, 8192, 1024, 512);                       // hi*lo
    gemm_k<2, EPI_BIAS | EPI_EMBED, true, true, false><<<dim3(64, 8), tb, 0, stream>>>(
        x, BtH, in_b, hbuf, nullptr, 8192, 1024, 512);                          // lo*hi + epilogue

    for (int L = 0; L < 4; ++L) {
        // ---- qkv ----
        if (L == 0) {
            // double-split: layer-0 scores are sigma~1024 (softmax ~ argmax) -> need ~fp32 q,k
            transpose_f2b<true><<<dim3(96, 32), tb, 0, stream>>>(
                qkv_W, BtH, BtL, 1024, 3072);
            gemm_k<1, 0, false, true, false><<<dim3(64, 24), tb, 0, stream>>>(
                hbuf, BtH, nullptr, qkvb, nullptr, 8192, 3072, 1024);
            gemm_k<1, 0, true, true, false><<<dim3(64, 24), tb, 0, stream>>>(
                hbuf, BtL, nullptr, qkvb, nullptr, 8192, 3072, 1024);
            gemm_k<2, EPI_BIAS, true, true, false><<<dim3(64, 24), tb, 0, stream>>>(
                hbuf, BtH, qkv_b, qkvb, nullptr, 8192, 3072, 1024);
        } else {
            transpose_f2b<false><<<dim3(96, 32), tb, 0, stream>>>(
                qkv_W + (size_t)L * 1024 * 3072, BtH, nullptr, 1024, 3072);
            gemm_k<1, EPI_BIAS, false, true, false><<<dim3(64, 24), tb, 0, stream>>>(
                hbuf, BtH, qkv_b + (size_t)L * 3072, qkvb, nullptr, 8192, 3072, 1024);
        }
        // ---- attention (MFMA flash, dbuf pipeline) ----
        attn_k<<<dim3(1024), tb, 0, stream>>>(qkvb, ctxb);
        // ---- out-proj + residual (ACCUM into h) + LN in-place ----
        transpose_f2b<false><<<dim3(32, 32), tb, 0, stream>>>(
            out_W + (size_t)L * 1024 * 1024, BtH, nullptr, 1024, 1024);
        gemm_k<0, EPI_BIAS, true, true, false><<<dim3(64, 8), tb, 0, stream>>>(
            ctxb, BtH, out_b + (size_t)L * 1024, hbuf, nullptr, 8192, 1024, 1024);
        ln_k<<<8192, tb, 0, stream>>>(hbuf, ln1_g + (size_t)L * 1024, ln1_b + (size_t)L * 1024);
        // ---- FF ----
        transpose_f2b<false><<<dim3(128, 32), tb, 0, stream>>>(
            ff1_W + (size_t)L * 1024 * 4096, BtH, nullptr, 1024, 4096);
        gemm_k<1, EPI_BIAS | EPI_RELU, false, false, true><<<dim3(64, 32), tb, 0, stream>>>(
            hbuf, BtH, ff1_b + (size_t)L * 4096, nullptr, (u16*)qkvb, 8192, 4096, 1024);
        transpose_f2b<false><<<dim3(32, 128), tb, 0, stream>>>(
            ff2_W + (size_t)L * 4096 * 1024, BtH, nullptr, 4096, 1024);
        gemm_k<0, EPI_BIAS, true, true, false><<<dim3(64, 8), tb, 0, stream>>>(
            (u16*)qkvb, BtH, ff2_b + (size_t)L * 1024, hbuf, nullptr, 8192, 1024, 4096);
        ln_k<<<8192, tb, 0, stream>>>(hbuf, ln2_g + (size_t)L * 1024, ln2_b + (size_t)L * 1024);
    }

    // ---- final LN (in-place) + output projection -> fp32 d_out ----
    ln_k<<<8192, tb, 0, stream>>>(hbuf, fin_g, fin_b);
    transpose_f2b<false><<<dim3(32, 32), tb, 0, stream>>>(op_W, BtH, nullptr, 1024, 1024);
    gemm_k<1, EPI_BIAS, false, true, false><<<dim3(64, 8), tb, 0, stream>>>(
        hbuf, BtH, op_b, (float*)d_out, nullptr, 8192, 1024, 1024);
}

// Round 4
// 2937.069 us; speedup vs baseline: 6.7142x; 1.0937x over previous
//
#include <hip/hip_runtime.h>
#include <math.h>

typedef unsigned short u16;
typedef __attribute__((ext_vector_type(8))) __bf16 bf16x8;
typedef __attribute__((ext_vector_type(4))) float floatx4;
typedef unsigned int __attribute__((address_space(1))) g_u32;
typedef unsigned int __attribute__((address_space(3))) l_u32;

#define EPI_BIAS  1
#define EPI_RELU  2
#define EPI_EMBED 8

__device__ __forceinline__ float bf2f(u16 u) {
    union { unsigned int i; float f; } v; v.i = ((unsigned int)u) << 16; return v.f;
}
// native convert: v_cvt_pk_bf16_f32 (RNE) — 1 op per 2 values.
__device__ __forceinline__ u16 f2bf(float f) {
    union { __bf16 b; u16 u; } v; v.b = (__bf16)f; return v.u;
}
// async 16B global->LDS DMA (lds dest = wave-uniform base + lane*16)
__device__ __forceinline__ void gl_lds16(const void* g, void* l) {
    __builtin_amdgcn_global_load_lds((const g_u32*)g, (l_u32*)l, 16, 0, 0);
}
// fp64 positional encoding (epilogue-only, embed GEMM; negligible cost)
__device__ __forceinline__ float posenc(int s, int c) {
    double e = exp((double)(c & 1022) * (-9.210340371976184 / 1024.0));
    double ang = (double)s * e;
    return (float)((c & 1) ? cos(ang) : sin(ang));
}

// ------- split convert: fp32 -> bf16 hi + lo (row-major, elementwise) -------
__global__ __launch_bounds__(256) void conv_split(
    const float* __restrict__ in, u16* __restrict__ oh, u16* __restrict__ ol) {
    const int i = (blockIdx.x * 256 + threadIdx.x) * 8;
    float4 a = ((const float4*)(in + i))[0];
    float4 b = ((const float4*)(in + i))[1];
    float f[8] = {a.x, a.y, a.z, a.w, b.x, b.y, b.z, b.w};
    union { u16 u[8]; uint4 q; } H, L;
    #pragma unroll
    for (int j = 0; j < 8; ++j) {
        u16 hi = f2bf(f[j]);
        H.u[j] = hi; L.u[j] = f2bf(f[j] - bf2f(hi));
    }
    *(uint4*)&oh[i] = H.q;
    *(uint4*)&ol[i] = L.q;
}

// --- transpose+convert: fp32 [R][C] -> bf16 [C][R]. TMODE 0: hi; 2: lo only ---
template<int TMODE>
__global__ __launch_bounds__(256) void transpose_f2b(
    const float* __restrict__ in, u16* __restrict__ oh,
    int R, int C) {
    __shared__ float tile[32][33];
    int bx = blockIdx.x * 32, by = blockIdx.y * 32;
    int tx = threadIdx.x & 31, ty = threadIdx.x >> 5; // ty 0..7
    #pragma unroll
    for (int i = ty; i < 32; i += 8) tile[i][tx] = in[(size_t)(by + i) * C + bx + tx];
    __syncthreads();
    #pragma unroll
    for (int i = ty; i < 32; i += 8) {
        float f = tile[tx][i];
        u16 hi = f2bf(f);
        u16 o = (TMODE == 2) ? f2bf(f - bf2f(hi)) : hi;
        oh[(size_t)(bx + i) * R + by + tx] = o;
    }
}

// ---------------- GEMM: C[M][N] = A[M][K] * Bt[N][K]^T, MFMA bf16 ----------------
// A is ALWAYS bf16 (u16): both tiles staged via global_load_lds DMA,
// zero staging VALU. WB writes bf16 hi; WB2 additionally writes bf16 lo.
template<int EPI, bool ACCUM, bool WF, bool WB, bool WB2>
__global__ __launch_bounds__(256) void gemm_k(
    const u16* __restrict__ A, const u16* __restrict__ Bt,
    const float* __restrict__ bias,
    float* __restrict__ outF, u16* __restrict__ outB, u16* __restrict__ outB2,
    int M, int N, int K) {
    __shared__ alignas(16) u16 As[128 * 32];
    __shared__ alignas(16) u16 Bs[128 * 32];
    const int tid = threadIdx.x;
    const int wave = tid >> 6, lane = tid & 63;
    const int l16 = lane & 15, quad = lane >> 4;
    const int bm = blockIdx.x * 128, bn = blockIdx.y * 128;
    const int wm = (wave & 1) * 64, wn = (wave >> 1) * 64;
    const int sr = tid >> 2, sc = (tid & 3) * 8;

    floatx4 acc[4][4];
    floatx4 zero = {0.0f, 0.0f, 0.0f, 0.0f};
    #pragma unroll
    for (int i = 0; i < 4; ++i)
        #pragma unroll
        for (int j = 0; j < 4; ++j) acc[i][j] = zero;

    for (int k0 = 0; k0 < K; k0 += 32) {
        #pragma unroll
        for (int p = 0; p < 2; ++p) {
            const u16* ga = A + (size_t)(bm + sr + 64 * p) * K + k0 + sc;
            gl_lds16(ga, &As[(p * 64 + (wave << 4)) * 32]);
        }
        #pragma unroll
        for (int p = 0; p < 2; ++p) {
            const u16* gb = Bt + (size_t)(bn + sr + 64 * p) * K + k0 + sc;
            gl_lds16(gb, &Bs[(p * 64 + (wave << 4)) * 32]);
        }
        __syncthreads();
        bf16x8 af[4], bfr[4];
        #pragma unroll
        for (int i = 0; i < 4; ++i) af[i] = *(const bf16x8*)&As[(wm + i * 16 + l16) * 32 + quad * 8];
        #pragma unroll
        for (int j = 0; j < 4; ++j) bfr[j] = *(const bf16x8*)&Bs[(wn + j * 16 + l16) * 32 + quad * 8];
        #pragma unroll
        for (int i = 0; i < 4; ++i)
            #pragma unroll
            for (int j = 0; j < 4; ++j)
                acc[i][j] = __builtin_amdgcn_mfma_f32_16x16x32_bf16(af[i], bfr[j], acc[i][j], 0, 0, 0);
        __syncthreads();
    }

    // ---- epilogue (C/D map: col=lane&15, row=quad*4+reg) ----
    #pragma unroll
    for (int i = 0; i < 4; ++i) {
        #pragma unroll
        for (int r = 0; r < 4; ++r) {
            int row = bm + wm + i * 16 + quad * 4 + r;
            #pragma unroll
            for (int j = 0; j < 4; ++j) {
                int col = bn + wn + j * 16 + l16;
                float v = acc[i][j][r];
                if (EPI & EPI_BIAS) v += bias[col];
                if (ACCUM) v += outF[(size_t)row * N + col];
                if (EPI & EPI_EMBED) { v = v * 32.0f + posenc(row & 2047, col); }
                if (EPI & EPI_RELU) v = fmaxf(v, 0.0f);
                if (WF) outF[(size_t)row * N + col] = v;
                if (WB) {
                    u16 hi = f2bf(v);
                    outB[(size_t)row * N + col] = hi;
                    if (WB2) outB2[(size_t)row * N + col] = f2bf(v - bf2f(hi));
                }
            }
        }
    }
}

// ---------------- attention v4: MFMA flash, dbuf pipeline, templated split -------
// grid = 64 bh * 16 qtiles; block = 256 (4 waves); each wave owns 32 q rows.
// SPLIT=true (layer 0): scores sigma~1024 -> 3-term split-bf16 QK^T.
// SPLIT=false (layers 1-3): post-LN scores sigma~1 -> single bf16 QK^T.
// T13 defer-rescale: skip O-rescale while chunk max stays within +8 of running max.
template<bool SPLIT>
__global__ __launch_bounds__(256) void attn_k(
    const float* __restrict__ qkv, u16* __restrict__ ctx) {
    constexpr int KSTR = 72;  // 144 B rows: b128 frag reads 2-way (free)
    constexpr int VSTR = 72;
    constexpr int PSTR = 88;  // 176 B rows: 16B-aligned
    __shared__ alignas(16) u16 Kh[2][64 * KSTR];
    __shared__ alignas(16) u16 Kl[2][SPLIT ? 64 * KSTR : 8];
    __shared__ alignas(16) u16 Vt[2][64 * VSTR];   // Vt[d][k]
    __shared__ alignas(16) u16 Ps[128 * PSTR];     // P[q][k]

    const int tid = threadIdx.x, wave = tid >> 6, lane = tid & 63;
    const int l16 = lane & 15, quad = lane >> 4;
    const int bh = blockIdx.x >> 4, qt = blockIdx.x & 15;
    const int b = bh >> 4, h = bh & 15;
    const size_t base = (size_t)b * 2048 * 3072;
    const int wq = wave * 32;

    // staging address bases (fixed per thread)
    const int kr = tid >> 2, kcb = (tid & 3) * 16;
    const float* gK = qkv + base + (size_t)kr * 3072 + 1024 + h * 64 + kcb;
    const int vk = lane, vdg = wave * 16;
    const float* gV = qkv + base + (size_t)vk * 3072 + 2048 + h * 64 + vdg;

    // ---- Q fragments in registers, pre-scaled by 1/8 (exact); hi/lo if SPLIT ----
    bf16x8 qh[2][2], ql[2][2];
    #pragma unroll
    for (int i = 0; i < 2; ++i) {
        const float* g = qkv + base + (size_t)(qt * 128 + wq + i * 16 + l16) * 3072 + h * 64 + quad * 8;
        #pragma unroll
        for (int kk = 0; kk < 2; ++kk) {
            float4 va = ((const float4*)(g + kk * 32))[0];
            float4 vb = ((const float4*)(g + kk * 32))[1];
            float f[8] = {va.x, va.y, va.z, va.w, vb.x, vb.y, vb.z, vb.w};
            union { u16 u[8]; bf16x8 v; } th, tl;
            #pragma unroll
            for (int j = 0; j < 8; ++j) {
                float s = f[j] * 0.125f;
                u16 hi = f2bf(s);
                th.u[j] = hi;
                if (SPLIT) tl.u[j] = f2bf(s - bf2f(hi));
            }
            qh[i][kk] = th.v;
            if (SPLIT) ql[i][kk] = tl.v;
        }
    }

    // prefetch registers (one K-chunk + one V-chunk per thread = 32 floats)
    float4 pk4[4], pv4[4];
    auto LOAD = [&](int c) {
        const float* g = gK + (size_t)(c * 64) * 3072;
        pk4[0] = ((const float4*)g)[0]; pk4[1] = ((const float4*)g)[1];
        pk4[2] = ((const float4*)g)[2]; pk4[3] = ((const float4*)g)[3];
        const float* g2 = gV + (size_t)(c * 64) * 3072;
        pv4[0] = ((const float4*)g2)[0]; pv4[1] = ((const float4*)g2)[1];
        pv4[2] = ((const float4*)g2)[2]; pv4[3] = ((const float4*)g2)[3];
    };
    auto STORE = [&](int bu) {
        const float* pf = (const float*)pk4;
        union { u16 u[8]; uint4 q; } h0, h1, s0, s1;
        #pragma unroll
        for (int j = 0; j < 8; ++j) {
            float a = pf[j], c2 = pf[8 + j];
            u16 ah = f2bf(a); h0.u[j] = ah;
            u16 ch = f2bf(c2); h1.u[j] = ch;
            if (SPLIT) { s0.u[j] = f2bf(a - bf2f(ah)); s1.u[j] = f2bf(c2 - bf2f(ch)); }
        }
        *(uint4*)&Kh[bu][kr * KSTR + kcb]     = h0.q;
        *(uint4*)&Kh[bu][kr * KSTR + kcb + 8] = h1.q;
        if (SPLIT) {
            *(uint4*)&Kl[bu][kr * KSTR + kcb]     = s0.q;
            *(uint4*)&Kl[bu][kr * KSTR + kcb + 8] = s1.q;
        }
        const float* vf = (const float*)pv4;
        #pragma unroll
        for (int j = 0; j < 16; ++j)
            Vt[bu][(vdg + j) * VSTR + vk] = f2bf(vf[j]);
    };

    floatx4 acc_o[2][4];
    float mrun[2][4], lrun[2][4];
    floatx4 zf = {0.0f, 0.0f, 0.0f, 0.0f};
    #pragma unroll
    for (int i = 0; i < 2; ++i)
        #pragma unroll
        for (int j = 0; j < 4; ++j) acc_o[i][j] = zf;
    #pragma unroll
    for (int i = 0; i < 2; ++i)
        #pragma unroll
        for (int r = 0; r < 4; ++r) { mrun[i][r] = -1e30f; lrun[i][r] = 0.0f; }

    // prologue: chunk0 -> buf0; chunk1 -> regs
    LOAD(0); STORE(0); LOAD(1);
    __syncthreads();

    for (int c = 0; c < 32; ++c) {
        const int cur = c & 1;

        // ---- QK^T: S-tile 32q x 64k per wave ----
        floatx4 acc_s[2][4];
        #pragma unroll
        for (int i = 0; i < 2; ++i)
            #pragma unroll
            for (int j = 0; j < 4; ++j) acc_s[i][j] = zf;
        #pragma unroll
        for (int kk = 0; kk < 2; ++kk) {
            bf16x8 kbh[4], kbl[4];
            #pragma unroll
            for (int j = 0; j < 4; ++j) {
                kbh[j] = *(const bf16x8*)&Kh[cur][(j * 16 + l16) * KSTR + kk * 32 + quad * 8];
                if (SPLIT) kbl[j] = *(const bf16x8*)&Kl[cur][(j * 16 + l16) * KSTR + kk * 32 + quad * 8];
            }
            __builtin_amdgcn_s_setprio(1);
            #pragma unroll
            for (int i = 0; i < 2; ++i)
                #pragma unroll
                for (int j = 0; j < 4; ++j) {
                    acc_s[i][j] = __builtin_amdgcn_mfma_f32_16x16x32_bf16(qh[i][kk], kbh[j], acc_s[i][j], 0, 0, 0);
                    if (SPLIT) {
                        acc_s[i][j] = __builtin_amdgcn_mfma_f32_16x16x32_bf16(ql[i][kk], kbh[j], acc_s[i][j], 0, 0, 0);
                        acc_s[i][j] = __builtin_amdgcn_mfma_f32_16x16x32_bf16(qh[i][kk], kbl[j], acc_s[i][j], 0, 0, 0);
                    }
                }
            __builtin_amdgcn_s_setprio(0);
        }

        // ---- online softmax with defer-rescale (T13, THR=8) ----
        float mx[2][4];
        #pragma unroll
        for (int i = 0; i < 2; ++i)
            #pragma unroll
            for (int r = 0; r < 4; ++r) {
                float m0 = fmaxf(fmaxf(acc_s[i][0][r], acc_s[i][1][r]),
                                 fmaxf(acc_s[i][2][r], acc_s[i][3][r]));
                #pragma unroll
                for (int off = 8; off; off >>= 1) m0 = fmaxf(m0, __shfl_xor(m0, off));
                mx[i][r] = m0;
            }
        bool up = false;
        #pragma unroll
        for (int i = 0; i < 2; ++i)
            #pragma unroll
            for (int r = 0; r < 4; ++r) up = up || (mx[i][r] > mrun[i][r] + 8.0f);
        if (__any(up)) {
            #pragma unroll
            for (int i = 0; i < 2; ++i)
                #pragma unroll
                for (int r = 0; r < 4; ++r) {
                    float nm = fmaxf(mrun[i][r], mx[i][r]);
                    float sc = __expf(mrun[i][r] - nm);
                    mrun[i][r] = nm;
                    lrun[i][r] *= sc;
                    #pragma unroll
                    for (int jd = 0; jd < 4; ++jd) acc_o[i][jd][r] *= sc;
                }
        }
        #pragma unroll
        for (int i = 0; i < 2; ++i)
            #pragma unroll
            for (int r = 0; r < 4; ++r) {
                float rs = 0.0f;
                #pragma unroll
                for (int j = 0; j < 4; ++j) {
                    float p = __expf(acc_s[i][j][r] - mrun[i][r]);
                    acc_s[i][j][r] = p;
                    rs += p;
                }
                #pragma unroll
                for (int off = 8; off; off >>= 1) rs += __shfl_xor(rs, off);
                lrun[i][r] += rs;
                #pragma unroll
                for (int j = 0; j < 4; ++j)
                    Ps[(wq + i * 16 + quad * 4 + r) * PSTR + j * 16 + l16] = f2bf(acc_s[i][j][r]);
            }
        // wave reads only its OWN Ps rows; same-wave DS ops are in-order, the
        // asm fence stops the compiler reordering the reads before writes.
        asm volatile("s_waitcnt lgkmcnt(0)" ::: "memory");

        // ---- PV: O[32q][64d] += P[32q][64k] * V[64k][64d] ----
        #pragma unroll
        for (int kk = 0; kk < 2; ++kk) {
            bf16x8 pa[2], vb[4];
            #pragma unroll
            for (int i = 0; i < 2; ++i)
                pa[i] = *(const bf16x8*)&Ps[(wq + i * 16 + l16) * PSTR + kk * 32 + quad * 8];
            #pragma unroll
            for (int jd = 0; jd < 4; ++jd)
                vb[jd] = *(const bf16x8*)&Vt[cur][(jd * 16 + l16) * VSTR + kk * 32 + quad * 8];
            __builtin_amdgcn_s_setprio(1);
            #pragma unroll
            for (int i = 0; i < 2; ++i)
                #pragma unroll
                for (int jd = 0; jd < 4; ++jd)
                    acc_o[i][jd] = __builtin_amdgcn_mfma_f32_16x16x32_bf16(pa[i], vb[jd], acc_o[i][jd], 0, 0, 0);
            __builtin_amdgcn_s_setprio(0);
        }

        // write prefetched chunk c+1 into the other buffer, then barrier
        if (c + 1 < 32) STORE(cur ^ 1);
        __syncthreads();
        if (c + 2 < 32) LOAD(c + 2);
    }

    // ---- epilogue: normalize and store ctx bf16 ----
    #pragma unroll
    for (int i = 0; i < 2; ++i) {
        #pragma unroll
        for (int r = 0; r < 4; ++r) {
            float inv = 1.0f / lrun[i][r];
            size_t ro = (size_t)(b * 2048 + qt * 128 + wq + i * 16 + quad * 4 + r) * 1024 + h * 64;
            #pragma unroll
            for (int jd = 0; jd < 4; ++jd)
                ctx[ro + jd * 16 + l16] = f2bf(acc_o[i][jd][r] * inv);
        }
    }
}

// ------- layernorm, in-place fp32 + bf16 copy for GEMM-A; one block per row -----
__global__ __launch_bounds__(256) void ln_k(
    float* __restrict__ h, const float* __restrict__ g, const float* __restrict__ bb,
    u16* __restrict__ hb) {
    const int row = blockIdx.x, tid = threadIdx.x;
    const int wave = tid >> 6, lane = tid & 63;
    float4 v = *(const float4*)(h + (size_t)row * 1024 + tid * 4);
    float x[4] = {v.x, v.y, v.z, v.w};
    float s = x[0] + x[1] + x[2] + x[3];
    float s2 = x[0] * x[0] + x[1] * x[1] + x[2] * x[2] + x[3] * x[3];
    for (int off = 32; off; off >>= 1) { s += __shfl_xor(s, off); s2 += __shfl_xor(s2, off); }
    __shared__ float red[8];
    if (lane == 0) { red[wave] = s; red[4 + wave] = s2; }
    __syncthreads();
    s = red[0] + red[1] + red[2] + red[3];
    s2 = red[4] + red[5] + red[6] + red[7];
    float mu = s * (1.0f / 1024.0f);
    float var = s2 * (1.0f / 1024.0f) - mu * mu;
    float rs = rsqrtf(var + 1e-5f);
    float4 gg = *(const float4*)(g + tid * 4);
    float4 bp = *(const float4*)(bb + tid * 4);
    float4 o;
    o.x = (x[0] - mu) * rs * gg.x + bp.x;
    o.y = (x[1] - mu) * rs * gg.y + bp.y;
    o.z = (x[2] - mu) * rs * gg.z + bp.z;
    o.w = (x[3] - mu) * rs * gg.w + bp.w;
    *(float4*)(h + (size_t)row * 1024 + tid * 4) = o;
    union { u16 u[4]; uint2 q; } hb4;
    hb4.u[0] = f2bf(o.x); hb4.u[1] = f2bf(o.y);
    hb4.u[2] = f2bf(o.z); hb4.u[3] = f2bf(o.w);
    *(uint2*)&hb[(size_t)row * 1024 + tid * 4] = hb4.q;
}

// ---------------- orchestration ----------------
extern "C" void kernel_launch(void* const* d_in, const int* in_sizes, int n_in,
                              void* d_out, int out_size, void* d_ws, size_t ws_size,
                              hipStream_t stream) {
    const float* x     = (const float*)d_in[0];
    const float* in_W  = (const float*)d_in[1];
    const float* in_b  = (const float*)d_in[2];
    const float* qkv_W = (const float*)d_in[3];
    const float* qkv_b = (const float*)d_in[4];
    const float* out_W = (const float*)d_in[5];
    const float* out_b = (const float*)d_in[6];
    const float* ln1_g = (const float*)d_in[7];
    const float* ln1_b = (const float*)d_in[8];
    const float* ln2_g = (const float*)d_in[9];
    const float* ln2_b = (const float*)d_in[10];
    const float* ff1_W = (const float*)d_in[11];
    const float* ff1_b = (const float*)d_in[12];
    const float* ff2_W = (const float*)d_in[13];
    const float* ff2_b = (const float*)d_in[14];
    const float* fin_g = (const float*)d_in[15];
    const float* fin_b = (const float*)d_in[16];
    const float* op_W  = (const float*)d_in[17];
    const float* op_b  = (const float*)d_in[18];

    // Workspace 168 MB (<=169 MB proven available). Aliasing windows:
    //  xh/xl (embed A)    -> qkvb region  (dead before qkv GEMMs write it)
    //  h0h (L0 qkv A hi)  -> ctxb region  (attn writes ctxb after qkv GEMMs)
    //  h0l (L0 qkv A lo)  -> hbfH region  (ln1 writes hbfH after qkv GEMMs)
    //  ffb (ff1 out bf16) -> qkvb region  (qkv dead after attn)
    // Split-B GEMMs reuse BtH for the lo plane via a second transpose pass
    // (no BtL buffer, no d_out scratch).
    size_t off = 0;
    char* wsb = (char*)d_ws;
    auto alloc = [&](size_t bytes) { void* p = wsb + off; off += (bytes + 255) & ~(size_t)255; return p; };
    u16*   BtH  = (u16*)alloc((size_t)4096 * 1024 * 2);      // 8 MB  rotating B^T
    float* hbuf = (float*)alloc((size_t)8192 * 1024 * 4);    // 32 MB fp32 hidden (resid)
    float* qkvb = (float*)alloc((size_t)8192 * 3072 * 4);    // 96 MB fp32 qkv / scratch
    u16*   ctxb = (u16*)alloc((size_t)8192 * 1024 * 2);      // 16 MB bf16 ctx
    u16*   hbfH = (u16*)alloc((size_t)8192 * 1024 * 2);      // 16 MB bf16 post-LN h
    if (off > ws_size) return;
    u16* xh  = (u16*)qkvb;
    u16* xl  = xh + (size_t)8192 * 512;
    u16* h0h = ctxb;
    u16* h0l = hbfH;
    u16* ffb = (u16*)qkvb;

    dim3 tb(256);

    // ---- embed: h = (x @ in_W + b)*32 + posenc, double-split (fp32-accurate h0) --
    // terms: xh*Wh + xl*Wh (BtH=hi), then xh*Wl (BtH=lo) + epilogue
    conv_split<<<dim3(2048), tb, 0, stream>>>(x, xh, xl);
    transpose_f2b<0><<<dim3(32, 16), tb, 0, stream>>>(in_W, BtH, 512, 1024);
    gemm_k<0, false, true, false, false><<<dim3(64, 8), tb, 0, stream>>>(
        xh, BtH, nullptr, hbuf, nullptr, nullptr, 8192, 1024, 512);
    gemm_k<0, true, true, false, false><<<dim3(64, 8), tb, 0, stream>>>(
        xl, BtH, nullptr, hbuf, nullptr, nullptr, 8192, 1024, 512);
    transpose_f2b<2><<<dim3(32, 16), tb, 0, stream>>>(in_W, BtH, 512, 1024);
    gemm_k<EPI_BIAS | EPI_EMBED, true, true, true, true><<<dim3(64, 8), tb, 0, stream>>>(
        xh, BtH, in_b, hbuf, h0h, h0l, 8192, 1024, 512);  // + epi; h0 hi/lo bf16

    for (int L = 0; L < 4; ++L) {
        // ---- qkv ----
        if (L == 0) {
            // double-split: layer-0 scores are sigma~1024 -> need ~fp32 q,k
            transpose_f2b<0><<<dim3(96, 32), tb, 0, stream>>>(qkv_W, BtH, 1024, 3072);
            gemm_k<0, false, true, false, false><<<dim3(64, 24), tb, 0, stream>>>(
                h0h, BtH, nullptr, qkvb, nullptr, nullptr, 8192, 3072, 1024);
            gemm_k<0, true, true, false, false><<<dim3(64, 24), tb, 0, stream>>>(
                h0l, BtH, nullptr, qkvb, nullptr, nullptr, 8192, 3072, 1024);
            transpose_f2b<2><<<dim3(96, 32), tb, 0, stream>>>(qkv_W, BtH, 1024, 3072);
            gemm_k<EPI_BIAS, true, true, false, false><<<dim3(64, 24), tb, 0, stream>>>(
                h0h, BtH, qkv_b, qkvb, nullptr, nullptr, 8192, 3072, 1024);
        } else {
            transpose_f2b<0><<<dim3(96, 32), tb, 0, stream>>>(
                qkv_W + (size_t)L * 1024 * 3072, BtH, 1024, 3072);
            gemm_k<EPI_BIAS, false, true, false, false><<<dim3(64, 24), tb, 0, stream>>>(
                hbfH, BtH, qkv_b + (size_t)L * 3072, qkvb, nullptr, nullptr, 8192, 3072, 1024);
        }
        // ---- attention (MFMA flash, dbuf pipeline) ----
        if (L == 0) attn_k<true><<<dim3(1024), tb, 0, stream>>>(qkvb, ctxb);
        else        attn_k<false><<<dim3(1024), tb, 0, stream>>>(qkvb, ctxb);
        // ---- out-proj + residual (ACCUM into h) + LN in-place ----
        transpose_f2b<0><<<dim3(32, 32), tb, 0, stream>>>(
            out_W + (size_t)L * 1024 * 1024, BtH, 1024, 1024);
        gemm_k<EPI_BIAS, true, true, false, false><<<dim3(64, 8), tb, 0, stream>>>(
            ctxb, BtH, out_b + (size_t)L * 1024, hbuf, nullptr, nullptr, 8192, 1024, 1024);
        ln_k<<<8192, tb, 0, stream>>>(hbuf, ln1_g + (size_t)L * 1024, ln1_b + (size_t)L * 1024, hbfH);
        // ---- FF ----
        transpose_f2b<0><<<dim3(128, 32), tb, 0, stream>>>(
            ff1_W + (size_t)L * 1024 * 4096, BtH, 1024, 4096);
        gemm_k<EPI_BIAS | EPI_RELU, false, false, true, false><<<dim3(64, 32), tb, 0, stream>>>(
            hbfH, BtH, ff1_b + (size_t)L * 4096, nullptr, ffb, nullptr, 8192, 4096, 1024);
        transpose_f2b<0><<<dim3(32, 128), tb, 0, stream>>>(
            ff2_W + (size_t)L * 4096 * 1024, BtH, 4096, 1024);
        gemm_k<EPI_BIAS, true, true, false, false><<<dim3(64, 8), tb, 0, stream>>>(
            ffb, BtH, ff2_b + (size_t)L * 1024, hbuf, nullptr, nullptr, 8192, 1024, 4096);
        ln_k<<<8192, tb, 0, stream>>>(hbuf, ln2_g + (size_t)L * 1024, ln2_b + (size_t)L * 1024, hbfH);
    }

    // ---- final LN + output projection -> fp32 d_out ----
    ln_k<<<8192, tb, 0, stream>>>(hbuf, fin_g, fin_b, hbfH);
    transpose_f2b<0><<<dim3(32, 32), tb, 0, stream>>>(op_W, BtH, 1024, 1024);
    gemm_k<EPI_BIAS, false, true, false, false><<<dim3(64, 8), tb, 0, stream>>>(
        hbfH, BtH, op_b, (float*)d_out, nullptr, nullptr, 8192, 1024, 1024);
}

// Round 5
// 2935.818 us; speedup vs baseline: 6.7171x; 1.0004x over previous
//
#include <hip/hip_runtime.h>
#include <math.h>

typedef unsigned short u16;
typedef __attribute__((ext_vector_type(8))) __bf16 bf16x8;
typedef __attribute__((ext_vector_type(4))) float floatx4;
typedef unsigned int __attribute__((address_space(1))) g_u32;
typedef unsigned int __attribute__((address_space(3))) l_u32;

#define EPI_BIAS  1
#define EPI_RELU  2
#define EPI_EMBED 8

__device__ __forceinline__ float bf2f(u16 u) {
    union { unsigned int i; float f; } v; v.i = ((unsigned int)u) << 16; return v.f;
}
// native convert: v_cvt_pk_bf16_f32 (RNE) — 1 op per 2 values.
__device__ __forceinline__ u16 f2bf(float f) {
    union { __bf16 b; u16 u; } v; v.b = (__bf16)f; return v.u;
}
// async 16B global->LDS DMA (lds dest = wave-uniform base + lane*16)
__device__ __forceinline__ void gl_lds16(const void* g, void* l) {
    __builtin_amdgcn_global_load_lds((const g_u32*)g, (l_u32*)l, 16, 0, 0);
}
// fp64 positional encoding (epilogue-only, embed GEMM; negligible cost)
__device__ __forceinline__ float posenc(int s, int c) {
    double e = exp((double)(c & 1022) * (-9.210340371976184 / 1024.0));
    double ang = (double)s * e;
    return (float)((c & 1) ? cos(ang) : sin(ang));
}

// ------- split convert: fp32 -> bf16 hi + lo (row-major, elementwise) -------
__global__ __launch_bounds__(256) void conv_split(
    const float* __restrict__ in, u16* __restrict__ oh, u16* __restrict__ ol) {
    const int i = (blockIdx.x * 256 + threadIdx.x) * 8;
    float4 a = ((const float4*)(in + i))[0];
    float4 b = ((const float4*)(in + i))[1];
    float f[8] = {a.x, a.y, a.z, a.w, b.x, b.y, b.z, b.w};
    union { u16 u[8]; uint4 q; } H, L;
    #pragma unroll
    for (int j = 0; j < 8; ++j) {
        u16 hi = f2bf(f[j]);
        H.u[j] = hi; L.u[j] = f2bf(f[j] - bf2f(hi));
    }
    *(uint4*)&oh[i] = H.q;
    *(uint4*)&ol[i] = L.q;
}

// --- transpose+convert: fp32 [R][C] -> bf16 [C][R]. TMODE 0: hi; 2: lo only ---
template<int TMODE>
__global__ __launch_bounds__(256) void transpose_f2b(
    const float* __restrict__ in, u16* __restrict__ oh,
    int R, int C) {
    __shared__ float tile[32][33];
    int bx = blockIdx.x * 32, by = blockIdx.y * 32;
    int tx = threadIdx.x & 31, ty = threadIdx.x >> 5; // ty 0..7
    #pragma unroll
    for (int i = ty; i < 32; i += 8) tile[i][tx] = in[(size_t)(by + i) * C + bx + tx];
    __syncthreads();
    #pragma unroll
    for (int i = ty; i < 32; i += 8) {
        float f = tile[tx][i];
        u16 hi = f2bf(f);
        u16 o = (TMODE == 2) ? f2bf(f - bf2f(hi)) : hi;
        oh[(size_t)(bx + i) * R + by + tx] = o;
    }
}

// ------- V^T prep (L1-3): bf16 qkv[8192][3072] V-cols -> vT[bh][64][2048] -------
__global__ __launch_bounds__(256) void transpose_v(
    const u16* __restrict__ q16, u16* __restrict__ vT) {
    __shared__ u16 tile[32][33];
    const int bh = blockIdx.y;               // 0..63 (= b*16 + h)
    const int b = bh >> 4, h = bh & 15;
    const int s0 = (blockIdx.x & 63) * 32;   // 64 s-tiles
    const int d0 = (blockIdx.x >> 6) * 32;   // 2 d-tiles
    const int tx = threadIdx.x & 31, ty = threadIdx.x >> 5;
    #pragma unroll
    for (int i = ty; i < 32; i += 8)
        tile[i][tx] = q16[(size_t)(b * 2048 + s0 + i) * 3072 + 2048 + h * 64 + d0 + tx];
    __syncthreads();
    #pragma unroll
    for (int i = ty; i < 32; i += 8)
        vT[((size_t)bh * 64 + d0 + i) * 2048 + s0 + tx] = tile[tx][i];
}

// ---------------- GEMM: C[M][N] = A[M][K] * Bt[N][K]^T, MFMA bf16 ----------------
// A is ALWAYS bf16 (u16): both tiles staged via global_load_lds DMA,
// zero staging VALU. WB writes bf16 hi; WB2 additionally writes bf16 lo.
template<int EPI, bool ACCUM, bool WF, bool WB, bool WB2>
__global__ __launch_bounds__(256) void gemm_k(
    const u16* __restrict__ A, const u16* __restrict__ Bt,
    const float* __restrict__ bias,
    float* __restrict__ outF, u16* __restrict__ outB, u16* __restrict__ outB2,
    int M, int N, int K) {
    __shared__ alignas(16) u16 As[128 * 32];
    __shared__ alignas(16) u16 Bs[128 * 32];
    const int tid = threadIdx.x;
    const int wave = tid >> 6, lane = tid & 63;
    const int l16 = lane & 15, quad = lane >> 4;
    const int bm = blockIdx.x * 128, bn = blockIdx.y * 128;
    const int wm = (wave & 1) * 64, wn = (wave >> 1) * 64;
    const int sr = tid >> 2, sc = (tid & 3) * 8;

    floatx4 acc[4][4];
    floatx4 zero = {0.0f, 0.0f, 0.0f, 0.0f};
    #pragma unroll
    for (int i = 0; i < 4; ++i)
        #pragma unroll
        for (int j = 0; j < 4; ++j) acc[i][j] = zero;

    for (int k0 = 0; k0 < K; k0 += 32) {
        #pragma unroll
        for (int p = 0; p < 2; ++p) {
            const u16* ga = A + (size_t)(bm + sr + 64 * p) * K + k0 + sc;
            gl_lds16(ga, &As[(p * 64 + (wave << 4)) * 32]);
        }
        #pragma unroll
        for (int p = 0; p < 2; ++p) {
            const u16* gb = Bt + (size_t)(bn + sr + 64 * p) * K + k0 + sc;
            gl_lds16(gb, &Bs[(p * 64 + (wave << 4)) * 32]);
        }
        __syncthreads();
        bf16x8 af[4], bfr[4];
        #pragma unroll
        for (int i = 0; i < 4; ++i) af[i] = *(const bf16x8*)&As[(wm + i * 16 + l16) * 32 + quad * 8];
        #pragma unroll
        for (int j = 0; j < 4; ++j) bfr[j] = *(const bf16x8*)&Bs[(wn + j * 16 + l16) * 32 + quad * 8];
        #pragma unroll
        for (int i = 0; i < 4; ++i)
            #pragma unroll
            for (int j = 0; j < 4; ++j)
                acc[i][j] = __builtin_amdgcn_mfma_f32_16x16x32_bf16(af[i], bfr[j], acc[i][j], 0, 0, 0);
        __syncthreads();
    }

    // ---- epilogue (C/D map: col=lane&15, row=quad*4+reg) ----
    #pragma unroll
    for (int i = 0; i < 4; ++i) {
        #pragma unroll
        for (int r = 0; r < 4; ++r) {
            int row = bm + wm + i * 16 + quad * 4 + r;
            #pragma unroll
            for (int j = 0; j < 4; ++j) {
                int col = bn + wn + j * 16 + l16;
                float v = acc[i][j][r];
                if (EPI & EPI_BIAS) v += bias[col];
                if (ACCUM) v += outF[(size_t)row * N + col];
                if (EPI & EPI_EMBED) { v = v * 32.0f + posenc(row & 2047, col); }
                if (EPI & EPI_RELU) v = fmaxf(v, 0.0f);
                if (WF) outF[(size_t)row * N + col] = v;
                if (WB) {
                    u16 hi = f2bf(v);
                    outB[(size_t)row * N + col] = hi;
                    if (WB2) outB2[(size_t)row * N + col] = f2bf(v - bf2f(hi));
                }
            }
        }
    }
}

// ------------- attention v4 (layer 0 only): fp32 src, split-bf16 QK^T -------------
// grid = 64 bh * 16 qtiles; block = 256 (4 waves); each wave owns 32 q rows.
__global__ __launch_bounds__(256) void attn_k(
    const float* __restrict__ qkv, u16* __restrict__ ctx) {
    constexpr int KSTR = 72;
    constexpr int VSTR = 72;
    constexpr int PSTR = 88;
    __shared__ alignas(16) u16 Kh[2][64 * KSTR];
    __shared__ alignas(16) u16 Kl[2][64 * KSTR];
    __shared__ alignas(16) u16 Vt[2][64 * VSTR];   // Vt[d][k]
    __shared__ alignas(16) u16 Ps[128 * PSTR];     // P[q][k]

    const int tid = threadIdx.x, wave = tid >> 6, lane = tid & 63;
    const int l16 = lane & 15, quad = lane >> 4;
    const int bh = blockIdx.x >> 4, qt = blockIdx.x & 15;
    const int b = bh >> 4, h = bh & 15;
    const size_t base = (size_t)b * 2048 * 3072;
    const int wq = wave * 32;

    const int kr = tid >> 2, kcb = (tid & 3) * 16;
    const float* gK = qkv + base + (size_t)kr * 3072 + 1024 + h * 64 + kcb;
    const int vk = lane, vdg = wave * 16;
    const float* gV = qkv + base + (size_t)vk * 3072 + 2048 + h * 64 + vdg;

    // Q fragments, pre-scaled by 1/8 (exact), hi/lo split
    bf16x8 qh[2][2], ql[2][2];
    #pragma unroll
    for (int i = 0; i < 2; ++i) {
        const float* g = qkv + base + (size_t)(qt * 128 + wq + i * 16 + l16) * 3072 + h * 64 + quad * 8;
        #pragma unroll
        for (int kk = 0; kk < 2; ++kk) {
            float4 va = ((const float4*)(g + kk * 32))[0];
            float4 vb = ((const float4*)(g + kk * 32))[1];
            float f[8] = {va.x, va.y, va.z, va.w, vb.x, vb.y, vb.z, vb.w};
            union { u16 u[8]; bf16x8 v; } th, tl;
            #pragma unroll
            for (int j = 0; j < 8; ++j) {
                float s = f[j] * 0.125f;
                u16 hi = f2bf(s);
                th.u[j] = hi;
                tl.u[j] = f2bf(s - bf2f(hi));
            }
            qh[i][kk] = th.v; ql[i][kk] = tl.v;
        }
    }

    float4 pk4[4], pv4[4];
    auto LOAD = [&](int c) {
        const float* g = gK + (size_t)(c * 64) * 3072;
        pk4[0] = ((const float4*)g)[0]; pk4[1] = ((const float4*)g)[1];
        pk4[2] = ((const float4*)g)[2]; pk4[3] = ((const float4*)g)[3];
        const float* g2 = gV + (size_t)(c * 64) * 3072;
        pv4[0] = ((const float4*)g2)[0]; pv4[1] = ((const float4*)g2)[1];
        pv4[2] = ((const float4*)g2)[2]; pv4[3] = ((const float4*)g2)[3];
    };
    auto STORE = [&](int bu) {
        const float* pf = (const float*)pk4;
        union { u16 u[8]; uint4 q; } h0, h1, s0, s1;
        #pragma unroll
        for (int j = 0; j < 8; ++j) {
            float a = pf[j], c2 = pf[8 + j];
            u16 ah = f2bf(a); h0.u[j] = ah; s0.u[j] = f2bf(a - bf2f(ah));
            u16 ch = f2bf(c2); h1.u[j] = ch; s1.u[j] = f2bf(c2 - bf2f(ch));
        }
        *(uint4*)&Kh[bu][kr * KSTR + kcb]     = h0.q;
        *(uint4*)&Kh[bu][kr * KSTR + kcb + 8] = h1.q;
        *(uint4*)&Kl[bu][kr * KSTR + kcb]     = s0.q;
        *(uint4*)&Kl[bu][kr * KSTR + kcb + 8] = s1.q;
        const float* vf = (const float*)pv4;
        #pragma unroll
        for (int j = 0; j < 16; ++j)
            Vt[bu][(vdg + j) * VSTR + vk] = f2bf(vf[j]);
    };

    floatx4 acc_o[2][4];
    float mrun[2][4], lrun[2][4];
    floatx4 zf = {0.0f, 0.0f, 0.0f, 0.0f};
    #pragma unroll
    for (int i = 0; i < 2; ++i)
        #pragma unroll
        for (int j = 0; j < 4; ++j) acc_o[i][j] = zf;
    #pragma unroll
    for (int i = 0; i < 2; ++i)
        #pragma unroll
        for (int r = 0; r < 4; ++r) { mrun[i][r] = -1e30f; lrun[i][r] = 0.0f; }

    LOAD(0); STORE(0); LOAD(1);
    __syncthreads();

    for (int c = 0; c < 32; ++c) {
        const int cur = c & 1;

        floatx4 acc_s[2][4];
        #pragma unroll
        for (int i = 0; i < 2; ++i)
            #pragma unroll
            for (int j = 0; j < 4; ++j) acc_s[i][j] = zf;
        #pragma unroll
        for (int kk = 0; kk < 2; ++kk) {
            bf16x8 kbh[4], kbl[4];
            #pragma unroll
            for (int j = 0; j < 4; ++j) {
                kbh[j] = *(const bf16x8*)&Kh[cur][(j * 16 + l16) * KSTR + kk * 32 + quad * 8];
                kbl[j] = *(const bf16x8*)&Kl[cur][(j * 16 + l16) * KSTR + kk * 32 + quad * 8];
            }
            __builtin_amdgcn_s_setprio(1);
            #pragma unroll
            for (int i = 0; i < 2; ++i)
                #pragma unroll
                for (int j = 0; j < 4; ++j) {
                    acc_s[i][j] = __builtin_amdgcn_mfma_f32_16x16x32_bf16(qh[i][kk], kbh[j], acc_s[i][j], 0, 0, 0);
                    acc_s[i][j] = __builtin_amdgcn_mfma_f32_16x16x32_bf16(ql[i][kk], kbh[j], acc_s[i][j], 0, 0, 0);
                    acc_s[i][j] = __builtin_amdgcn_mfma_f32_16x16x32_bf16(qh[i][kk], kbl[j], acc_s[i][j], 0, 0, 0);
                }
            __builtin_amdgcn_s_setprio(0);
        }

        // online softmax with defer-rescale (THR=8)
        float mx[2][4];
        #pragma unroll
        for (int i = 0; i < 2; ++i)
            #pragma unroll
            for (int r = 0; r < 4; ++r) {
                float m0 = fmaxf(fmaxf(acc_s[i][0][r], acc_s[i][1][r]),
                                 fmaxf(acc_s[i][2][r], acc_s[i][3][r]));
                #pragma unroll
                for (int off = 8; off; off >>= 1) m0 = fmaxf(m0, __shfl_xor(m0, off));
                mx[i][r] = m0;
            }
        bool up = false;
        #pragma unroll
        for (int i = 0; i < 2; ++i)
            #pragma unroll
            for (int r = 0; r < 4; ++r) up = up || (mx[i][r] > mrun[i][r] + 8.0f);
        if (__any(up)) {
            #pragma unroll
            for (int i = 0; i < 2; ++i)
                #pragma unroll
                for (int r = 0; r < 4; ++r) {
                    float nm = fmaxf(mrun[i][r], mx[i][r]);
                    float sc = __expf(mrun[i][r] - nm);
                    mrun[i][r] = nm;
                    lrun[i][r] *= sc;
                    #pragma unroll
                    for (int jd = 0; jd < 4; ++jd) acc_o[i][jd][r] *= sc;
                }
        }
        #pragma unroll
        for (int i = 0; i < 2; ++i)
            #pragma unroll
            for (int r = 0; r < 4; ++r) {
                float rs = 0.0f;
                #pragma unroll
                for (int j = 0; j < 4; ++j) {
                    float p = __expf(acc_s[i][j][r] - mrun[i][r]);
                    acc_s[i][j][r] = p;
                    rs += p;
                }
                #pragma unroll
                for (int off = 8; off; off >>= 1) rs += __shfl_xor(rs, off);
                lrun[i][r] += rs;
                #pragma unroll
                for (int j = 0; j < 4; ++j)
                    Ps[(wq + i * 16 + quad * 4 + r) * PSTR + j * 16 + l16] = f2bf(acc_s[i][j][r]);
            }
        asm volatile("s_waitcnt lgkmcnt(0)" ::: "memory");

        #pragma unroll
        for (int kk = 0; kk < 2; ++kk) {
            bf16x8 pa[2], vb[4];
            #pragma unroll
            for (int i = 0; i < 2; ++i)
                pa[i] = *(const bf16x8*)&Ps[(wq + i * 16 + l16) * PSTR + kk * 32 + quad * 8];
            #pragma unroll
            for (int jd = 0; jd < 4; ++jd)
                vb[jd] = *(const bf16x8*)&Vt[cur][(jd * 16 + l16) * VSTR + kk * 32 + quad * 8];
            __builtin_amdgcn_s_setprio(1);
            #pragma unroll
            for (int i = 0; i < 2; ++i)
                #pragma unroll
                for (int jd = 0; jd < 4; ++jd)
                    acc_o[i][jd] = __builtin_amdgcn_mfma_f32_16x16x32_bf16(pa[i], vb[jd], acc_o[i][jd], 0, 0, 0);
            __builtin_amdgcn_s_setprio(0);
        }

        if (c + 1 < 32) STORE(cur ^ 1);
        __syncthreads();
        if (c + 2 < 32) LOAD(c + 2);
    }

    #pragma unroll
    for (int i = 0; i < 2; ++i) {
        #pragma unroll
        for (int r = 0; r < 4; ++r) {
            float inv = 1.0f / lrun[i][r];
            size_t ro = (size_t)(b * 2048 + qt * 128 + wq + i * 16 + quad * 4 + r) * 1024 + h * 64;
            #pragma unroll
            for (int jd = 0; jd < 4; ++jd)
                ctx[ro + jd * 16 + l16] = f2bf(acc_o[i][jd][r] * inv);
        }
    }
}

// ------------- attention v5 (layers 1-3): pure-DMA bf16 K/V^T staging -------------
// Sources: qkvh bf16 [8192][3072] (from qkv GEMM), vT bf16 [64bh][64][2048].
// K/V LDS tiles are [64][64] linear (DMA-written) with XOR-swizzled source cols
// and XOR-swizzled reads (rule #21: both-sides-or-neither). Zero staging VALU.
__global__ __launch_bounds__(256) void attn2_k(
    const u16* __restrict__ qkvh, const u16* __restrict__ vT,
    u16* __restrict__ ctx) {
    constexpr int PSTR = 72;
    __shared__ alignas(16) u16 Kh[2][64 * 64];
    __shared__ alignas(16) u16 Vt[2][64 * 64];
    __shared__ alignas(16) u16 Ps[128 * PSTR];

    const int tid = threadIdx.x, wave = tid >> 6, lane = tid & 63;
    const int l16 = lane & 15, quad = lane >> 4;
    const int bh = blockIdx.x >> 4, qt = blockIdx.x & 15;
    const int b = bh >> 4, h = bh & 15;
    const int wq = wave * 32;

    // per-thread DMA source geometry (row = p*32 + tid/8, colunit = tid%8 ^ row%8)
    const int r8 = tid >> 3;
    const int cusw = (tid & 7) ^ (r8 & 7);
    const u16* gK = qkvh + (size_t)(b * 2048 + r8) * 3072 + 1024 + h * 64 + cusw * 8;
    const u16* gV = vT + ((size_t)bh * 64 + r8) * 2048 + cusw * 8;
    // LDS dest base (wave-uniform): byte = p*4096 + wave*1024
    const int ldst = (wave << 9);

    auto STAGE = [&](int c, int bu) {
        #pragma unroll
        for (int p = 0; p < 2; ++p) {
            gl_lds16(gK + (size_t)(c * 64 + p * 32) * 3072, &Kh[bu][p * 2048 + ldst]);
            gl_lds16(gV + (size_t)(p * 32) * 2048 + c * 64, &Vt[bu][p * 2048 + ldst]);
        }
    };

    // Q fragments from bf16 qkv, scaled by 1/8 (exact in bf16)
    bf16x8 qh[2][2];
    #pragma unroll
    for (int i = 0; i < 2; ++i) {
        const u16* g = qkvh + (size_t)(b * 2048 + qt * 128 + wq + i * 16 + l16) * 3072 + h * 64;
        #pragma unroll
        for (int kk = 0; kk < 2; ++kk) {
            union { u16 u[8]; bf16x8 v; uint4 q; } t;
            t.q = *(const uint4*)(g + kk * 32 + quad * 8);
            #pragma unroll
            for (int j = 0; j < 8; ++j) t.u[j] = f2bf(bf2f(t.u[j]) * 0.125f);
            qh[i][kk] = t.v;
        }
    }

    floatx4 acc_o[2][4];
    float mrun[2][4], lrun[2][4];
    floatx4 zf = {0.0f, 0.0f, 0.0f, 0.0f};
    #pragma unroll
    for (int i = 0; i < 2; ++i)
        #pragma unroll
        for (int j = 0; j < 4; ++j) acc_o[i][j] = zf;
    #pragma unroll
    for (int i = 0; i < 2; ++i)
        #pragma unroll
        for (int r = 0; r < 4; ++r) { mrun[i][r] = -1e30f; lrun[i][r] = 0.0f; }

    STAGE(0, 0);
    __syncthreads();   // drains vmcnt(0): chunk0 resident

    for (int c = 0; c < 32; ++c) {
        const int cur = c & 1;
        if (c + 1 < 32) STAGE(c + 1, cur ^ 1);  // in flight across whole compute phase

        // ---- QK^T (XOR-swizzled reads) ----
        floatx4 acc_s[2][4];
        #pragma unroll
        for (int i = 0; i < 2; ++i)
            #pragma unroll
            for (int j = 0; j < 4; ++j) acc_s[i][j] = zf;
        #pragma unroll
        for (int kk = 0; kk < 2; ++kk) {
            bf16x8 kb[4];
            #pragma unroll
            for (int j = 0; j < 4; ++j) {
                int row = j * 16 + l16;
                int cu = (kk * 4 + quad) ^ (row & 7);
                kb[j] = *(const bf16x8*)&Kh[cur][row * 64 + cu * 8];
            }
            __builtin_amdgcn_s_setprio(1);
            #pragma unroll
            for (int i = 0; i < 2; ++i)
                #pragma unroll
                for (int j = 0; j < 4; ++j)
                    acc_s[i][j] = __builtin_amdgcn_mfma_f32_16x16x32_bf16(qh[i][kk], kb[j], acc_s[i][j], 0, 0, 0);
            __builtin_amdgcn_s_setprio(0);
        }

        // ---- online softmax with defer-rescale (THR=8) ----
        float mx[2][4];
        #pragma unroll
        for (int i = 0; i < 2; ++i)
            #pragma unroll
            for (int r = 0; r < 4; ++r) {
                float m0 = fmaxf(fmaxf(acc_s[i][0][r], acc_s[i][1][r]),
                                 fmaxf(acc_s[i][2][r], acc_s[i][3][r]));
                #pragma unroll
                for (int off = 8; off; off >>= 1) m0 = fmaxf(m0, __shfl_xor(m0, off));
                mx[i][r] = m0;
            }
        bool up = false;
        #pragma unroll
        for (int i = 0; i < 2; ++i)
            #pragma unroll
            for (int r = 0; r < 4; ++r) up = up || (mx[i][r] > mrun[i][r] + 8.0f);
        if (__any(up)) {
            #pragma unroll
            for (int i = 0; i < 2; ++i)
                #pragma unroll
                for (int r = 0; r < 4; ++r) {
                    float nm = fmaxf(mrun[i][r], mx[i][r]);
                    float sc = __expf(mrun[i][r] - nm);
                    mrun[i][r] = nm;
                    lrun[i][r] *= sc;
                    #pragma unroll
                    for (int jd = 0; jd < 4; ++jd) acc_o[i][jd][r] *= sc;
                }
        }
        #pragma unroll
        for (int i = 0; i < 2; ++i)
            #pragma unroll
            for (int r = 0; r < 4; ++r) {
                float rs = 0.0f;
                #pragma unroll
                for (int j = 0; j < 4; ++j) {
                    float p = __expf(acc_s[i][j][r] - mrun[i][r]);
                    acc_s[i][j][r] = p;
                    rs += p;
                }
                #pragma unroll
                for (int off = 8; off; off >>= 1) rs += __shfl_xor(rs, off);
                lrun[i][r] += rs;
                #pragma unroll
                for (int j = 0; j < 4; ++j)
                    Ps[(wq + i * 16 + quad * 4 + r) * PSTR + j * 16 + l16] = f2bf(acc_s[i][j][r]);
            }
        // wave reads only its OWN Ps rows; fence stops read-before-write reorder
        asm volatile("s_waitcnt lgkmcnt(0)" ::: "memory");

        // ---- PV (XOR-swizzled V reads) ----
        #pragma unroll
        for (int kk = 0; kk < 2; ++kk) {
            bf16x8 pa[2], vb[4];
            #pragma unroll
            for (int i = 0; i < 2; ++i)
                pa[i] = *(const bf16x8*)&Ps[(wq + i * 16 + l16) * PSTR + kk * 32 + quad * 8];
            #pragma unroll
            for (int jd = 0; jd < 4; ++jd) {
                int row = jd * 16 + l16;
                int cu = (kk * 4 + quad) ^ (row & 7);
                vb[jd] = *(const bf16x8*)&Vt[cur][row * 64 + cu * 8];
            }
            __builtin_amdgcn_s_setprio(1);
            #pragma unroll
            for (int i = 0; i < 2; ++i)
                #pragma unroll
                for (int jd = 0; jd < 4; ++jd)
                    acc_o[i][jd] = __builtin_amdgcn_mfma_f32_16x16x32_bf16(pa[i], vb[jd], acc_o[i][jd], 0, 0, 0);
            __builtin_amdgcn_s_setprio(0);
        }

        __syncthreads();  // drains vmcnt(0)+lgkmcnt: next buffer ready, this one free
    }

    // ---- epilogue ----
    #pragma unroll
    for (int i = 0; i < 2; ++i) {
        #pragma unroll
        for (int r = 0; r < 4; ++r) {
            float inv = 1.0f / lrun[i][r];
            size_t ro = (size_t)(b * 2048 + qt * 128 + wq + i * 16 + quad * 4 + r) * 1024 + h * 64;
            #pragma unroll
            for (int jd = 0; jd < 4; ++jd)
                ctx[ro + jd * 16 + l16] = f2bf(acc_o[i][jd][r] * inv);
        }
    }
}

// ------- layernorm, in-place fp32 + bf16 copy for GEMM-A; one block per row -----
__global__ __launch_bounds__(256) void ln_k(
    float* __restrict__ h, const float* __restrict__ g, const float* __restrict__ bb,
    u16* __restrict__ hb) {
    const int row = blockIdx.x, tid = threadIdx.x;
    const int wave = tid >> 6, lane = tid & 63;
    float4 v = *(const float4*)(h + (size_t)row * 1024 + tid * 4);
    float x[4] = {v.x, v.y, v.z, v.w};
    float s = x[0] + x[1] + x[2] + x[3];
    float s2 = x[0] * x[0] + x[1] * x[1] + x[2] * x[2] + x[3] * x[3];
    for (int off = 32; off; off >>= 1) { s += __shfl_xor(s, off); s2 += __shfl_xor(s2, off); }
    __shared__ float red[8];
    if (lane == 0) { red[wave] = s; red[4 + wave] = s2; }
    __syncthreads();
    s = red[0] + red[1] + red[2] + red[3];
    s2 = red[4] + red[5] + red[6] + red[7];
    float mu = s * (1.0f / 1024.0f);
    float var = s2 * (1.0f / 1024.0f) - mu * mu;
    float rs = rsqrtf(var + 1e-5f);
    float4 gg = *(const float4*)(g + tid * 4);
    float4 bp = *(const float4*)(bb + tid * 4);
    float4 o;
    o.x = (x[0] - mu) * rs * gg.x + bp.x;
    o.y = (x[1] - mu) * rs * gg.y + bp.y;
    o.z = (x[2] - mu) * rs * gg.z + bp.z;
    o.w = (x[3] - mu) * rs * gg.w + bp.w;
    *(float4*)(h + (size_t)row * 1024 + tid * 4) = o;
    union { u16 u[4]; uint2 q; } hb4;
    hb4.u[0] = f2bf(o.x); hb4.u[1] = f2bf(o.y);
    hb4.u[2] = f2bf(o.z); hb4.u[3] = f2bf(o.w);
    *(uint2*)&hb[(size_t)row * 1024 + tid * 4] = hb4.q;
}

// ---------------- orchestration ----------------
extern "C" void kernel_launch(void* const* d_in, const int* in_sizes, int n_in,
                              void* d_out, int out_size, void* d_ws, size_t ws_size,
                              hipStream_t stream) {
    const float* x     = (const float*)d_in[0];
    const float* in_W  = (const float*)d_in[1];
    const float* in_b  = (const float*)d_in[2];
    const float* qkv_W = (const float*)d_in[3];
    const float* qkv_b = (const float*)d_in[4];
    const float* out_W = (const float*)d_in[5];
    const float* out_b = (const float*)d_in[6];
    const float* ln1_g = (const float*)d_in[7];
    const float* ln1_b = (const float*)d_in[8];
    const float* ln2_g = (const float*)d_in[9];
    const float* ln2_b = (const float*)d_in[10];
    const float* ff1_W = (const float*)d_in[11];
    const float* ff1_b = (const float*)d_in[12];
    const float* ff2_W = (const float*)d_in[13];
    const float* ff2_b = (const float*)d_in[14];
    const float* fin_g = (const float*)d_in[15];
    const float* fin_b = (const float*)d_in[16];
    const float* op_W  = (const float*)d_in[17];
    const float* op_b  = (const float*)d_in[18];

    // Workspace 168 MB. Aliasing windows (stream-ordered liveness):
    //  xh/xl (embed A)      -> qkvb   (dead before qkv GEMMs write it)
    //  h0h (L0 qkv A hi)    -> ctxb   (attn writes ctxb after qkv GEMMs)
    //  h0l (L0 qkv A lo)    -> hbfH   (ln1 writes hbfH after attn)
    //  qkvH (L1-3 bf16 qkv) -> qkvb   (fp32 qkv not used for L1-3)
    //  vT (L1-3 V^T bf16)   -> hbfH   (prev-layer hbfH dead after qkv GEMM reads it)
    //  ffb (ff1 out bf16)   -> qkvb   (qkv dead after attn)
    size_t off = 0;
    char* wsb = (char*)d_ws;
    auto alloc = [&](size_t bytes) { void* p = wsb + off; off += (bytes + 255) & ~(size_t)255; return p; };
    u16*   BtH  = (u16*)alloc((size_t)4096 * 1024 * 2);      // 8 MB  rotating B^T
    float* hbuf = (float*)alloc((size_t)8192 * 1024 * 4);    // 32 MB fp32 hidden (resid)
    float* qkvb = (float*)alloc((size_t)8192 * 3072 * 4);    // 96 MB fp32 qkv / scratch
    u16*   ctxb = (u16*)alloc((size_t)8192 * 1024 * 2);      // 16 MB bf16 ctx
    u16*   hbfH = (u16*)alloc((size_t)8192 * 1024 * 2);      // 16 MB bf16 post-LN h
    if (off > ws_size) return;
    u16* xh   = (u16*)qkvb;
    u16* xl   = xh + (size_t)8192 * 512;
    u16* h0h  = ctxb;
    u16* h0l  = hbfH;
    u16* qkvH = (u16*)qkvb;
    u16* vTb  = hbfH;
    u16* ffb  = (u16*)qkvb;

    dim3 tb(256);

    // ---- embed: h = (x @ in_W + b)*32 + posenc, double-split (fp32-accurate h0) --
    conv_split<<<dim3(2048), tb, 0, stream>>>(x, xh, xl);
    transpose_f2b<0><<<dim3(32, 16), tb, 0, stream>>>(in_W, BtH, 512, 1024);
    gemm_k<0, false, true, false, false><<<dim3(64, 8), tb, 0, stream>>>(
        xh, BtH, nullptr, hbuf, nullptr, nullptr, 8192, 1024, 512);
    gemm_k<0, true, true, false, false><<<dim3(64, 8), tb, 0, stream>>>(
        xl, BtH, nullptr, hbuf, nullptr, nullptr, 8192, 1024, 512);
    transpose_f2b<2><<<dim3(32, 16), tb, 0, stream>>>(in_W, BtH, 512, 1024);
    gemm_k<EPI_BIAS | EPI_EMBED, true, true, true, true><<<dim3(64, 8), tb, 0, stream>>>(
        xh, BtH, in_b, hbuf, h0h, h0l, 8192, 1024, 512);  // + epi; h0 hi/lo bf16

    for (int L = 0; L < 4; ++L) {
        if (L == 0) {
            // double-split qkv (scores sigma~1024 need ~fp32 q,k) -> fp32 qkvb
            transpose_f2b<0><<<dim3(96, 32), tb, 0, stream>>>(qkv_W, BtH, 1024, 3072);
            gemm_k<0, false, true, false, false><<<dim3(64, 24), tb, 0, stream>>>(
                h0h, BtH, nullptr, qkvb, nullptr, nullptr, 8192, 3072, 1024);
            gemm_k<0, true, true, false, false><<<dim3(64, 24), tb, 0, stream>>>(
                h0l, BtH, nullptr, qkvb, nullptr, nullptr, 8192, 3072, 1024);
            transpose_f2b<2><<<dim3(96, 32), tb, 0, stream>>>(qkv_W, BtH, 1024, 3072);
            gemm_k<EPI_BIAS, true, true, false, false><<<dim3(64, 24), tb, 0, stream>>>(
                h0h, BtH, qkv_b, qkvb, nullptr, nullptr, 8192, 3072, 1024);
            attn_k<<<dim3(1024), tb, 0, stream>>>(qkvb, ctxb);
        } else {
            // bf16-out qkv GEMM -> DMA attention
            transpose_f2b<0><<<dim3(96, 32), tb, 0, stream>>>(
                qkv_W + (size_t)L * 1024 * 3072, BtH, 1024, 3072);
            gemm_k<EPI_BIAS, false, false, true, false><<<dim3(64, 24), tb, 0, stream>>>(
                hbfH, BtH, qkv_b + (size_t)L * 3072, nullptr, qkvH, nullptr, 8192, 3072, 1024);
            transpose_v<<<dim3(128, 64), tb, 0, stream>>>(qkvH, vTb);
            attn2_k<<<dim3(1024), tb, 0, stream>>>(qkvH, vTb, ctxb);
        }
        // ---- out-proj + residual (ACCUM into h) + LN ----
        transpose_f2b<0><<<dim3(32, 32), tb, 0, stream>>>(
            out_W + (size_t)L * 1024 * 1024, BtH, 1024, 1024);
        gemm_k<EPI_BIAS, true, true, false, false><<<dim3(64, 8), tb, 0, stream>>>(
            ctxb, BtH, out_b + (size_t)L * 1024, hbuf, nullptr, nullptr, 8192, 1024, 1024);
        ln_k<<<8192, tb, 0, stream>>>(hbuf, ln1_g + (size_t)L * 1024, ln1_b + (size_t)L * 1024, hbfH);
        // ---- FF ----
        transpose_f2b<0><<<dim3(128, 32), tb, 0, stream>>>(
            ff1_W + (size_t)L * 1024 * 4096, BtH, 1024, 4096);
        gemm_k<EPI_BIAS | EPI_RELU, false, false, true, false><<<dim3(64, 32), tb, 0, stream>>>(
            hbfH, BtH, ff1_b + (size_t)L * 4096, nullptr, ffb, nullptr, 8192, 4096, 1024);
        transpose_f2b<0><<<dim3(32, 128), tb, 0, stream>>>(
            ff2_W + (size_t)L * 4096 * 1024, BtH, 4096, 1024);
        gemm_k<EPI_BIAS, true, true, false, false><<<dim3(64, 8), tb, 0, stream>>>(
            ffb, BtH, ff2_b + (size_t)L * 1024, hbuf, nullptr, nullptr, 8192, 1024, 4096);
        ln_k<<<8192, tb, 0, stream>>>(hbuf, ln2_g + (size_t)L * 1024, ln2_b + (size_t)L * 1024, hbfH);
    }

    // ---- final LN + output projection -> fp32 d_out ----
    ln_k<<<8192, tb, 0, stream>>>(hbuf, fin_g, fin_b, hbfH);
    transpose_f2b<0><<<dim3(32, 32), tb, 0, stream>>>(op_W, BtH, 1024, 1024);
    gemm_k<EPI_BIAS, false, true, false, false><<<dim3(64, 8), tb, 0, stream>>>(
        hbfH, BtH, op_b, (float*)d_out, nullptr, nullptr, 8192, 1024, 1024);
}